// Round 1
// baseline (575.952 us; speedup 1.0000x reference)
//
#include <hip/hip_runtime.h>
#include <hip/hip_cooperative_groups.h>

namespace cg = cooperative_groups;

#define N_NODES 50000
#define N_EDGES 800000
#define F 64
#define NTILES (N_NODES / 16)                  // 3125

#define BNODES 128                             // nodes per bucket
#define NB ((N_NODES + BNODES - 1) / BNODES)   // 391 buckets
#define BCAP 2560                              // bucket capacity (mean 2046, +25% slack)
#define EPB 2048                               // edges per scatter chunk (4/thread @512)
#define SCHUNKS ((N_EDGES + EPB - 1) / EPB)    // 391 (last chunk 1280)
#define GRID 512                               // 2 blocks/CU co-resident
#define BLOCK 512
#define NWAVES (GRID * BLOCK / 64)             // 4096 waves
#define NGRP16 (GRID * BLOCK / 16)             // 16384 16-lane groups
#define PREP_ELEMS (4 * F * F + N_NODES * 16)  // W entries + float4 groups

typedef __attribute__((ext_vector_type(8))) short short8;   // 8 bf16 (4 VGPRs)
typedef __attribute__((ext_vector_type(4))) float f32x4;    // MFMA accumulator

union frag16 { uint4 u; short8 s; };

// ---------------- bf16 helpers (storage-only; all math fp32/MFMA) ----------------

__device__ __forceinline__ float bflo(unsigned int u) {
    union { unsigned int i; float f; } c; c.i = u << 16; return c.f;
}
__device__ __forceinline__ float bfhi(unsigned int u) {
    union { unsigned int i; float f; } c; c.i = u & 0xFFFF0000u; return c.f;
}
__device__ __forceinline__ unsigned short f2bf(float f) {   // round-nearest-even
    union { float f; unsigned int i; } c; c.f = f;
    unsigned int r = c.i + 0x7FFF + ((c.i >> 16) & 1);
    return (unsigned short)(r >> 16);
}

// ---------------- shared-memory union across phases ----------------

union SMem {
    struct {
        int lcnt[NB];
        int scan[BLOCK];
        int gbase[NB];
        int lcur[NB];
        unsigned int staged[EPB];
    } sc;                                      // scatter phase: ~14.6 KB
    struct {
        int ncnt[BNODES];
        int nofs[BNODES];
        int ncur[BNODES];
    } bk;                                      // bucket phase
};

// ============================ phase 0: scatter + prep ============================
// all blocks: W fp32[k][n]->bf16 W^T[n][k] (4 mats) + x fp32->bf16 (grid-stride)
// blocks < SCHUNKS: stage EPB edges (src/dst register-cached: ONE global read),
// group by bucket in LDS, reserve global ranges, write grouped.
// packed edge: src (bits 0-15) | dst_local (bits 16-22) | bucket (bits 23-31)

__device__ void phase_scatter_prep(
        const int* __restrict__ src, const int* __restrict__ dst,
        int* __restrict__ bcur, unsigned int* __restrict__ binned,
        const float* __restrict__ W0, const float* __restrict__ W1,
        const float* __restrict__ W2, const float* __restrict__ W3,
        unsigned short* __restrict__ Wt,
        const float4* __restrict__ xin, ushort4* __restrict__ xout,
        SMem& sm) {
    int tid = threadIdx.x;
    int blk = blockIdx.x;

    // ---- prep slice (independent of scatter; ~3 elems/thread) ----
    for (int idx = blk * BLOCK + tid; idx < PREP_ELEMS; idx += GRID * BLOCK) {
        if (idx < 4 * F * F) {
            int m = idx >> 12;
            int e = idx & 4095;
            int n = e >> 6, k = e & 63;
            const float* W = (m == 0) ? W0 : (m == 1) ? W1 : (m == 2) ? W2 : W3;
            Wt[m * F * F + n * F + k] = f2bf(W[k * F + n]);
        } else {
            int i = idx - 4 * F * F;
            float4 v = xin[i];
            ushort4 o;
            o.x = f2bf(v.x); o.y = f2bf(v.y); o.z = f2bf(v.z); o.w = f2bf(v.w);
            xout[i] = o;
        }
    }

    if (blk >= SCHUNKS) return;                // block-uniform: whole block skips

    int e0 = blk * EPB;
    int e1 = min(N_EDGES, e0 + EPB);
    for (int i = tid; i < NB; i += BLOCK) sm.sc.lcnt[i] = 0;
    __syncthreads();

    // register-cache the edges: one global read instead of two
    int dreg[4], sreg[4];
    #pragma unroll
    for (int t = 0; t < 4; ++t) {
        int i = e0 + tid + t * BLOCK;
        if (i < e1) { dreg[t] = dst[i]; sreg[t] = src[i]; }
        else        { dreg[t] = -1;     sreg[t] = 0; }
    }
    #pragma unroll
    for (int t = 0; t < 4; ++t)
        if (dreg[t] >= 0) atomicAdd(&sm.sc.lcnt[dreg[t] >> 7], 1);
    __syncthreads();

    int v = (tid < NB) ? sm.sc.lcnt[tid] : 0;
    sm.sc.scan[tid] = v;
    __syncthreads();
    for (int off = 1; off < BLOCK; off <<= 1) {
        int t2 = (tid >= off) ? sm.sc.scan[tid - off] : 0;
        __syncthreads();
        sm.sc.scan[tid] += t2;
        __syncthreads();
    }
    if (tid < NB) {
        int excl = sm.sc.scan[tid] - v;
        int resv = (v > 0) ? atomicAdd(&bcur[tid], v) : 0;
        sm.sc.gbase[tid] = tid * BCAP + resv - excl;
        sm.sc.lcur[tid] = excl;
    }
    __syncthreads();

    #pragma unroll
    for (int t = 0; t < 4; ++t) {
        if (dreg[t] >= 0) {
            int d = dreg[t];
            int b = d >> 7;
            int dl = d & 127;
            int posl = atomicAdd(&sm.sc.lcur[b], 1);
            sm.sc.staged[posl] =
                (unsigned)sreg[t] | ((unsigned)dl << 16) | ((unsigned)b << 23);
        }
    }
    __syncthreads();

    int cnt = e1 - e0;
    for (int i = tid; i < cnt; i += BLOCK) {
        unsigned pk = sm.sc.staged[i];
        binned[sm.sc.gbase[pk >> 23] + i] = pk;   // grouped -> mostly coalesced
    }
}

// ============================ phase 1: bucket CSR build ============================
// per bucket: node counts + local scan -> row_beg/degs/csr16 (binned reg-cached)

__device__ void phase_bucket(
        const unsigned int* __restrict__ binned, const int* __restrict__ bcur,
        int* __restrict__ row_beg, unsigned short* __restrict__ degs,
        unsigned short* __restrict__ csr16, SMem& sm) {
    int blk = blockIdx.x;
    if (blk >= NB) return;                     // block-uniform
    int tid = threadIdx.x;
    int start = blk * BCAP;
    int cnt = min(bcur[blk], BCAP);

    for (int i = tid; i < BNODES; i += BLOCK) sm.bk.ncnt[i] = 0;
    __syncthreads();

    // register-cache bucket entries: one global read instead of two
    unsigned preg[5];
    #pragma unroll
    for (int t = 0; t < 5; ++t) {
        int i = tid + t * BLOCK;
        preg[t] = (i < cnt) ? binned[start + i] : 0xFFFFFFFFu;
    }
    #pragma unroll
    for (int t = 0; t < 5; ++t)
        if (preg[t] != 0xFFFFFFFFu)
            atomicAdd(&sm.bk.ncnt[(preg[t] >> 16) & 127], 1);
    __syncthreads();

    if (tid < BNODES) sm.bk.nofs[tid] = sm.bk.ncnt[tid];
    __syncthreads();
    for (int off = 1; off < BNODES; off <<= 1) {
        int t2 = (tid >= off && tid < BNODES) ? sm.bk.nofs[tid - off] : 0;
        __syncthreads();
        if (tid < BNODES) sm.bk.nofs[tid] += t2;
        __syncthreads();
    }
    if (tid < BNODES) {
        int excl = sm.bk.nofs[tid] - sm.bk.ncnt[tid];
        sm.bk.ncur[tid] = excl;
        int node = blk * BNODES + tid;
        row_beg[node] = start + excl;
        degs[node] = (unsigned short)sm.bk.ncnt[tid];
    }
    __syncthreads();

    #pragma unroll
    for (int t = 0; t < 5; ++t) {
        if (preg[t] != 0xFFFFFFFFu) {
            unsigned pk = preg[t];
            int dl = (pk >> 16) & 127;
            int pos = start + atomicAdd(&sm.bk.ncur[dl], 1);
            csr16[pos] = (unsigned short)(pk & 0xFFFF);
        }
    }
}

// ========== phase 2/4: aggregation — wave/node, 8 groups x 8 lanes, 2 chains ==========

__device__ void aggregate_phase(
        const uint4* __restrict__ xh8, const int* __restrict__ row_beg,
        const unsigned short* __restrict__ degs,
        const unsigned short* __restrict__ csr16, uint4* __restrict__ aggh8,
        int gwave, int lane) {
    int g   = lane >> 3;    // edge group 0..7
    int sub = lane & 7;     // ushort8 (8 feats, 16B) within the 64-feat row
    for (int node = gwave; node < N_NODES; node += NWAVES) {
        int beg = row_beg[node];
        int deg = degs[node];
        int end = beg + deg;
        float a0[8], a1[8];
        #pragma unroll
        for (int j = 0; j < 8; ++j) { a0[j] = 0.f; a1[j] = 0.f; }
        int i = beg + g;
        for (; i + 8 < end; i += 16) {   // 2 chains x 8 groups = 16 edges in flight
            int i0 = csr16[i];
            int i1 = csr16[i + 8];
            uint4 v0 = xh8[i0 * 8 + sub];
            uint4 v1 = xh8[i1 * 8 + sub];
            a0[0] += bflo(v0.x); a0[1] += bfhi(v0.x); a0[2] += bflo(v0.y); a0[3] += bfhi(v0.y);
            a0[4] += bflo(v0.z); a0[5] += bfhi(v0.z); a0[6] += bflo(v0.w); a0[7] += bfhi(v0.w);
            a1[0] += bflo(v1.x); a1[1] += bfhi(v1.x); a1[2] += bflo(v1.y); a1[3] += bfhi(v1.y);
            a1[4] += bflo(v1.z); a1[5] += bfhi(v1.z); a1[6] += bflo(v1.w); a1[7] += bfhi(v1.w);
        }
        if (i < end) {
            uint4 v0 = xh8[csr16[i] * 8 + sub];
            a0[0] += bflo(v0.x); a0[1] += bfhi(v0.x); a0[2] += bflo(v0.y); a0[3] += bfhi(v0.y);
            a0[4] += bflo(v0.z); a0[5] += bfhi(v0.z); a0[6] += bflo(v0.w); a0[7] += bfhi(v0.w);
        }
        float s[8];
        #pragma unroll
        for (int j = 0; j < 8; ++j) s[j] = a0[j] + a1[j];
        #pragma unroll
        for (int off = 8; off <= 32; off <<= 1)
            #pragma unroll
            for (int j = 0; j < 8; ++j)
                s[j] += __shfl_xor(s[j], off);
        if (g == 0) {
            float inv = (deg > 0) ? (1.0f / (float)deg) : 0.f;
            unsigned short o[8];
            #pragma unroll
            for (int j = 0; j < 8; ++j) o[j] = f2bf(s[j] * inv);
            uint4 pk;
            pk.x = (unsigned)o[0] | ((unsigned)o[1] << 16);
            pk.y = (unsigned)o[2] | ((unsigned)o[3] << 16);
            pk.z = (unsigned)o[4] | ((unsigned)o[5] << 16);
            pk.w = (unsigned)o[6] | ((unsigned)o[7] << 16);
            aggh8[node * 8 + sub] = pk;
        }
    }
}

// ========== phase 3/5: MFMA transform h = relu(x@Ws + agg@Wn + b) ==========
// wave per 16-node tile, grid-stride; W/bias fragments hoisted out of tile loop.
// PROJ=true additionally fuses the layer-3 projection into p (neigh) / q (self).

template <bool PROJ>
__device__ void transform_phase(
        const uint4* __restrict__ xh, const uint4* __restrict__ aggh,
        const uint4* __restrict__ Wst, const uint4* __restrict__ Wnt,
        const float* __restrict__ b, unsigned short* __restrict__ out_bf,
        const float* __restrict__ Ws3, const float* __restrict__ Wn3,
        float* __restrict__ pout, float* __restrict__ qout,
        int gwave, int lane) {
    int lo = lane & 15, hi = lane >> 4;

    frag16 ws[2][4], wn[2][4];
    #pragma unroll
    for (int kt = 0; kt < 2; ++kt)
        #pragma unroll
        for (int jt = 0; jt < 4; ++jt) {
            int n = jt * 16 + lo;
            ws[kt][jt].u = Wst[n * 8 + kt * 4 + hi];
            wn[kt][jt].u = Wnt[n * 8 + kt * 4 + hi];
        }
    float bias_s[4];
    #pragma unroll
    for (int jt = 0; jt < 4; ++jt) bias_s[jt] = b[jt * 16 + lo];
    float w3n_s[4], w3s_s[4];
    if constexpr (PROJ) {
        #pragma unroll
        for (int jt = 0; jt < 4; ++jt) {
            w3n_s[jt] = Wn3[jt * 16 + lo];
            w3s_s[jt] = Ws3[jt * 16 + lo];
        }
    }

    for (int tile = gwave; tile < NTILES; tile += NWAVES) {
        int base = tile * 16;
        int node = base + lo;

        frag16 ax[2], aa[2];
        #pragma unroll
        for (int kt = 0; kt < 2; ++kt) {
            ax[kt].u = xh[node * 8 + kt * 4 + hi];
            aa[kt].u = aggh[node * 8 + kt * 4 + hi];
        }

        f32x4 acc[4];
        #pragma unroll
        for (int jt = 0; jt < 4; ++jt)
            acc[jt] = f32x4{bias_s[jt], bias_s[jt], bias_s[jt], bias_s[jt]};

        #pragma unroll
        for (int kt = 0; kt < 2; ++kt)
            #pragma unroll
            for (int jt = 0; jt < 4; ++jt) {
                acc[jt] = __builtin_amdgcn_mfma_f32_16x16x32_bf16(ax[kt].s, ws[kt][jt].s, acc[jt], 0, 0, 0);
                acc[jt] = __builtin_amdgcn_mfma_f32_16x16x32_bf16(aa[kt].s, wn[kt][jt].s, acc[jt], 0, 0, 0);
            }

        if constexpr (!PROJ) {
            #pragma unroll
            for (int jt = 0; jt < 4; ++jt)
                #pragma unroll
                for (int r = 0; r < 4; ++r) {
                    float h = fmaxf(acc[jt][r], 0.f);
                    out_bf[(base + hi * 4 + r) * F + jt * 16 + lo] = f2bf(h);
                }
        } else {
            #pragma unroll
            for (int r = 0; r < 4; ++r) {
                float pr = 0.f, qr = 0.f;
                #pragma unroll
                for (int jt = 0; jt < 4; ++jt) {
                    float h = fmaxf(acc[jt][r], 0.f);
                    pr += h * w3n_s[jt];
                    qr += h * w3s_s[jt];
                }
                #pragma unroll
                for (int off = 1; off < 16; off <<= 1) {
                    pr += __shfl_xor(pr, off);
                    qr += __shfl_xor(qr, off);
                }
                if (lo == 0) {
                    pout[base + hi * 4 + r] = pr;
                    qout[base + hi * 4 + r] = qr;
                }
            }
        }
    }
}

// ========== phase 6: out = q + mean_agg(p) + b3, 16 lanes per node ==========

__device__ void final_phase(
        const int* __restrict__ row_beg, const unsigned short* __restrict__ degs,
        const unsigned short* __restrict__ csr16,
        const float* __restrict__ p, const float* __restrict__ q,
        const float* __restrict__ b3, float* __restrict__ out,
        int blk, int tid) {
    int ggrp = (blk * BLOCK + tid) >> 4;
    int ln = tid & 15;
    for (int node = ggrp; node < N_NODES; node += NGRP16) {
        int beg = row_beg[node];
        int deg = degs[node];
        int end = beg + deg;
        float s = 0.f;
        for (int i = beg + ln; i < end; i += 16) s += p[csr16[i]];
        #pragma unroll
        for (int off = 1; off < 16; off <<= 1) s += __shfl_xor(s, off);
        if (ln == 0) {
            float inv = (deg > 0) ? (1.0f / (float)deg) : 0.f;
            out[node] = q[node] + s * inv + b3[0];
        }
    }
}

// ============================ fused cooperative kernel ============================

__global__ __launch_bounds__(BLOCK, 4) void fused_all(
        const float* __restrict__ x, const int* __restrict__ src,
        const int* __restrict__ dst,
        const float* __restrict__ W0, const float* __restrict__ W1,
        const float* __restrict__ W2, const float* __restrict__ W3,
        const float* __restrict__ b1, const float* __restrict__ b2,
        const float* __restrict__ Ws3, const float* __restrict__ Wn3,
        const float* __restrict__ b3,
        int* __restrict__ bcur, unsigned int* __restrict__ binned,
        int* __restrict__ row_beg, unsigned short* __restrict__ degs,
        unsigned short* __restrict__ csr16, unsigned short* __restrict__ xh,
        unsigned short* __restrict__ h1h, unsigned short* __restrict__ aggh,
        unsigned short* __restrict__ Wt, float* __restrict__ p,
        float* __restrict__ q, float* __restrict__ out) {
    cg::grid_group grid = cg::this_grid();
    __shared__ SMem sm;
    int tid = threadIdx.x;
    int lane = tid & 63;
    int gwave = (blockIdx.x * BLOCK + tid) >> 6;

    phase_scatter_prep(src, dst, bcur, binned, W0, W1, W2, W3, Wt,
                       (const float4*)x, (ushort4*)xh, sm);
    grid.sync();
    phase_bucket(binned, bcur, row_beg, degs, csr16, sm);
    grid.sync();
    aggregate_phase((const uint4*)xh, row_beg, degs, csr16, (uint4*)aggh, gwave, lane);
    grid.sync();
    transform_phase<false>((const uint4*)xh, (const uint4*)aggh,
                           (const uint4*)Wt, (const uint4*)(Wt + F * F), b1,
                           h1h, nullptr, nullptr, nullptr, nullptr, gwave, lane);
    grid.sync();
    aggregate_phase((const uint4*)h1h, row_beg, degs, csr16, (uint4*)aggh, gwave, lane);
    grid.sync();
    transform_phase<true>((const uint4*)h1h, (const uint4*)aggh,
                          (const uint4*)(Wt + 2 * F * F), (const uint4*)(Wt + 3 * F * F), b2,
                          nullptr, Ws3, Wn3, p, q, gwave, lane);
    grid.sync();
    final_phase(row_beg, degs, csr16, p, q, b3, out, blockIdx.x, tid);
}

// ------------- fallback wrappers (identical phase code, 7 plain launches) -------------

__global__ __launch_bounds__(BLOCK, 4) void k_scatter_prep(
        const int* src, const int* dst, int* bcur, unsigned int* binned,
        const float* W0, const float* W1, const float* W2, const float* W3,
        unsigned short* Wt, const float4* xin, ushort4* xout) {
    __shared__ SMem sm;
    phase_scatter_prep(src, dst, bcur, binned, W0, W1, W2, W3, Wt, xin, xout, sm);
}

__global__ __launch_bounds__(BLOCK, 4) void k_bucket(
        const unsigned int* binned, const int* bcur, int* row_beg,
        unsigned short* degs, unsigned short* csr16) {
    __shared__ SMem sm;
    phase_bucket(binned, bcur, row_beg, degs, csr16, sm);
}

__global__ __launch_bounds__(BLOCK, 4) void k_aggregate(
        const uint4* xh8, const int* row_beg, const unsigned short* degs,
        const unsigned short* csr16, uint4* aggh8) {
    int gwave = (blockIdx.x * BLOCK + threadIdx.x) >> 6;
    aggregate_phase(xh8, row_beg, degs, csr16, aggh8, gwave, threadIdx.x & 63);
}

__global__ __launch_bounds__(BLOCK, 4) void k_tf_mid(
        const uint4* xh, const uint4* aggh, const uint4* Wst, const uint4* Wnt,
        const float* b, unsigned short* out_bf) {
    int gwave = (blockIdx.x * BLOCK + threadIdx.x) >> 6;
    transform_phase<false>(xh, aggh, Wst, Wnt, b, out_bf,
                           nullptr, nullptr, nullptr, nullptr, gwave, threadIdx.x & 63);
}

__global__ __launch_bounds__(BLOCK, 4) void k_tf_last(
        const uint4* xh, const uint4* aggh, const uint4* Wst, const uint4* Wnt,
        const float* b, const float* Ws3, const float* Wn3, float* p, float* q) {
    int gwave = (blockIdx.x * BLOCK + threadIdx.x) >> 6;
    transform_phase<true>(xh, aggh, Wst, Wnt, b, nullptr,
                          Ws3, Wn3, p, q, gwave, threadIdx.x & 63);
}

__global__ __launch_bounds__(BLOCK, 4) void k_final(
        const int* row_beg, const unsigned short* degs, const unsigned short* csr16,
        const float* p, const float* q, const float* b3, float* out) {
    final_phase(row_beg, degs, csr16, p, q, b3, out, blockIdx.x, threadIdx.x);
}

// ---------------- launch ----------------

extern "C" void kernel_launch(void* const* d_in, const int* in_sizes, int n_in,
                              void* d_out, int out_size, void* d_ws, size_t ws_size,
                              hipStream_t stream) {
    const float* x   = (const float*)d_in[0];
    const int*   src = (const int*)d_in[1];
    const int*   dst = (const int*)d_in[2];
    const float* Ws1 = (const float*)d_in[3];
    const float* Wn1 = (const float*)d_in[4];
    const float* b1  = (const float*)d_in[5];
    const float* Ws2 = (const float*)d_in[6];
    const float* Wn2 = (const float*)d_in[7];
    const float* b2  = (const float*)d_in[8];
    const float* Ws3 = (const float*)d_in[9];
    const float* Wn3 = (const float*)d_in[10];
    const float* b3  = (const float*)d_in[11];
    float* out = (float*)d_out;

    char* ws = (char*)d_ws;
    size_t cur = 0;
    auto alloc = [&](size_t bytes) -> void* {
        void* ptr = ws + cur;
        cur += (bytes + 255) & ~(size_t)255;
        return ptr;
    };

    int*            bcur     = (int*)  alloc(NB * sizeof(int));
    unsigned int*   binned   = (unsigned int*)alloc((size_t)NB * BCAP * sizeof(unsigned int));
    int*            row_beg  = (int*)  alloc((size_t)(NB * BNODES) * sizeof(int));
    unsigned short* degs     = (unsigned short*)alloc((size_t)(NB * BNODES) * sizeof(unsigned short));
    unsigned short* csr16    = (unsigned short*)alloc((size_t)NB * BCAP * sizeof(unsigned short));
    unsigned short* xh       = (unsigned short*)alloc((size_t)N_NODES * F * 2);  // bf16 x
    unsigned short* h1h      = (unsigned short*)alloc((size_t)N_NODES * F * 2);  // bf16 h1
    unsigned short* aggh     = (unsigned short*)alloc((size_t)N_NODES * F * 2);  // bf16 agg
    unsigned short* Wt       = (unsigned short*)alloc(4 * F * F * 2);            // bf16 W^T x4
    float*          p        = (float*)alloc(N_NODES * sizeof(float));
    float*          q        = (float*)alloc(N_NODES * sizeof(float));

    (void)hipMemsetAsync(bcur, 0, NB * sizeof(int), stream);

    void* ka[] = {
        (void*)&x, (void*)&src, (void*)&dst,
        (void*)&Ws1, (void*)&Wn1, (void*)&Ws2, (void*)&Wn2,
        (void*)&b1, (void*)&b2, (void*)&Ws3, (void*)&Wn3, (void*)&b3,
        (void*)&bcur, (void*)&binned, (void*)&row_beg, (void*)&degs,
        (void*)&csr16, (void*)&xh, (void*)&h1h, (void*)&aggh,
        (void*)&Wt, (void*)&p, (void*)&q, (void*)&out
    };
    hipError_t err = hipLaunchCooperativeKernel(
        (void*)fused_all, dim3(GRID), dim3(BLOCK), ka, 0, stream);

    if (err != hipSuccess) {
        // fallback: identical phase code as 7 plain launches
        k_scatter_prep<<<GRID, BLOCK, 0, stream>>>(
            src, dst, bcur, binned, Ws1, Wn1, Ws2, Wn2, Wt,
            (const float4*)x, (ushort4*)xh);
        k_bucket<<<NB, BLOCK, 0, stream>>>(binned, bcur, row_beg, degs, csr16);
        k_aggregate<<<GRID, BLOCK, 0, stream>>>(
            (const uint4*)xh, row_beg, degs, csr16, (uint4*)aggh);
        k_tf_mid<<<GRID, BLOCK, 0, stream>>>(
            (const uint4*)xh, (const uint4*)aggh,
            (const uint4*)Wt, (const uint4*)(Wt + F * F), b1, h1h);
        k_aggregate<<<GRID, BLOCK, 0, stream>>>(
            (const uint4*)h1h, row_beg, degs, csr16, (uint4*)aggh);
        k_tf_last<<<GRID, BLOCK, 0, stream>>>(
            (const uint4*)h1h, (const uint4*)aggh,
            (const uint4*)(Wt + 2 * F * F), (const uint4*)(Wt + 3 * F * F), b2,
            Ws3, Wn3, p, q);
        k_final<<<GRID, BLOCK, 0, stream>>>(row_beg, degs, csr16, p, q, b3, out);
    }
}

// Round 2
// 167.921 us; speedup vs baseline: 3.4299x; 3.4299x over previous
//
#include <hip/hip_runtime.h>

#define N_NODES 50000
#define N_EDGES 800000
#define F 64
#define NTILES (N_NODES / 16)                  // 3125

#define BNODES 128                             // nodes per bucket
#define NB ((N_NODES + BNODES - 1) / BNODES)   // 391 buckets
#define BCAP 2560                              // bucket capacity (mean 2046, +25% slack)
#define EPB 2048                               // edges per scatter chunk (4/thread @512)
#define SCHUNKS ((N_EDGES + EPB - 1) / EPB)    // 391 (last chunk 1280)
#define SGRID 512                              // scatter_prep grid
#define SBLOCK 512
#define PREP_ELEMS (4 * F * F + N_NODES * 16)  // W entries + float4 groups

typedef __attribute__((ext_vector_type(8))) short short8;   // 8 bf16 (4 VGPRs)
typedef __attribute__((ext_vector_type(4))) float f32x4;    // MFMA accumulator

union frag16 { uint4 u; short8 s; };

// ---------------- bf16 helpers (storage-only; all math fp32/MFMA) ----------------

__device__ __forceinline__ float bflo(unsigned int u) {
    union { unsigned int i; float f; } c; c.i = u << 16; return c.f;
}
__device__ __forceinline__ float bfhi(unsigned int u) {
    union { unsigned int i; float f; } c; c.i = u & 0xFFFF0000u; return c.f;
}
__device__ __forceinline__ unsigned short f2bf(float f) {   // round-nearest-even
    union { float f; unsigned int i; } c; c.f = f;
    unsigned int r = c.i + 0x7FFF + ((c.i >> 16) & 1);
    return (unsigned short)(r >> 16);
}

// ============================ scatter + prep ============================
// all blocks: W fp32[k][n]->bf16 W^T[n][k] (4 mats) + x fp32->bf16 (grid-stride)
// blocks < SCHUNKS: stage EPB edges (src/dst register-cached: ONE global read),
// group by bucket in LDS, reserve global ranges, write grouped.
// packed edge: src (bits 0-15) | dst_local (bits 16-22) | bucket (bits 23-31)

__global__ __launch_bounds__(SBLOCK) void scatter_prep(
        const int* __restrict__ src, const int* __restrict__ dst,
        int* __restrict__ bcur, unsigned int* __restrict__ binned,
        const float* __restrict__ W0, const float* __restrict__ W1,
        const float* __restrict__ W2, const float* __restrict__ W3,
        unsigned short* __restrict__ Wt,
        const float4* __restrict__ xin, ushort4* __restrict__ xout) {
    __shared__ int lcnt[NB];
    __shared__ int scan[SBLOCK];
    __shared__ int gbase[NB];
    __shared__ int lcur[NB];
    __shared__ unsigned int staged[EPB];

    int tid = threadIdx.x;
    int blk = blockIdx.x;

    // ---- prep slice (independent of scatter) ----
    for (int idx = blk * SBLOCK + tid; idx < PREP_ELEMS; idx += SGRID * SBLOCK) {
        if (idx < 4 * F * F) {
            int m = idx >> 12;
            int e = idx & 4095;
            int n = e >> 6, k = e & 63;
            const float* W = (m == 0) ? W0 : (m == 1) ? W1 : (m == 2) ? W2 : W3;
            Wt[m * F * F + n * F + k] = f2bf(W[k * F + n]);
        } else {
            int i = idx - 4 * F * F;
            float4 v = xin[i];
            ushort4 o;
            o.x = f2bf(v.x); o.y = f2bf(v.y); o.z = f2bf(v.z); o.w = f2bf(v.w);
            xout[i] = o;
        }
    }

    if (blk >= SCHUNKS) return;                // block-uniform: whole block skips

    int e0 = blk * EPB;
    int e1 = min(N_EDGES, e0 + EPB);
    for (int i = tid; i < NB; i += SBLOCK) lcnt[i] = 0;
    __syncthreads();

    // register-cache the edges: one global read instead of two
    int dreg[4], sreg[4];
    #pragma unroll
    for (int t = 0; t < 4; ++t) {
        int i = e0 + tid + t * SBLOCK;
        if (i < e1) { dreg[t] = dst[i]; sreg[t] = src[i]; }
        else        { dreg[t] = -1;     sreg[t] = 0; }
    }
    #pragma unroll
    for (int t = 0; t < 4; ++t)
        if (dreg[t] >= 0) atomicAdd(&lcnt[dreg[t] >> 7], 1);
    __syncthreads();

    int v = (tid < NB) ? lcnt[tid] : 0;
    scan[tid] = v;
    __syncthreads();
    for (int off = 1; off < SBLOCK; off <<= 1) {
        int t2 = (tid >= off) ? scan[tid - off] : 0;
        __syncthreads();
        scan[tid] += t2;
        __syncthreads();
    }
    if (tid < NB) {
        int excl = scan[tid] - v;
        int resv = (v > 0) ? atomicAdd(&bcur[tid], v) : 0;
        gbase[tid] = tid * BCAP + resv - excl;
        lcur[tid] = excl;
    }
    __syncthreads();

    #pragma unroll
    for (int t = 0; t < 4; ++t) {
        if (dreg[t] >= 0) {
            int d = dreg[t];
            int b = d >> 7;
            int dl = d & 127;
            int posl = atomicAdd(&lcur[b], 1);
            staged[posl] = (unsigned)sreg[t] | ((unsigned)dl << 16) | ((unsigned)b << 23);
        }
    }
    __syncthreads();

    int cnt = e1 - e0;
    for (int i = tid; i < cnt; i += SBLOCK) {
        unsigned pk = staged[i];
        binned[gbase[pk >> 23] + i] = pk;      // grouped -> mostly coalesced
    }
}

// ============================ bucket CSR build ============================
// per bucket: node counts + local scan -> row_beg/degs/csr16 (binned reg-cached)

__global__ __launch_bounds__(512) void bucket_build(
        const unsigned int* __restrict__ binned, const int* __restrict__ bcur,
        int* __restrict__ row_beg, unsigned short* __restrict__ degs,
        unsigned short* __restrict__ csr16) {
    __shared__ int ncnt[BNODES];
    __shared__ int nofs[BNODES];
    __shared__ int ncur[BNODES];
    int blk = blockIdx.x;
    int tid = threadIdx.x;
    int start = blk * BCAP;
    int cnt = min(bcur[blk], BCAP);

    for (int i = tid; i < BNODES; i += 512) ncnt[i] = 0;
    __syncthreads();

    // register-cache bucket entries: one global read instead of two
    unsigned preg[5];
    #pragma unroll
    for (int t = 0; t < 5; ++t) {
        int i = tid + t * 512;
        preg[t] = (i < cnt) ? binned[start + i] : 0xFFFFFFFFu;
    }
    #pragma unroll
    for (int t = 0; t < 5; ++t)
        if (preg[t] != 0xFFFFFFFFu)
            atomicAdd(&ncnt[(preg[t] >> 16) & 127], 1);
    __syncthreads();

    if (tid < BNODES) nofs[tid] = ncnt[tid];
    __syncthreads();
    for (int off = 1; off < BNODES; off <<= 1) {
        int t2 = (tid >= off && tid < BNODES) ? nofs[tid - off] : 0;
        __syncthreads();
        if (tid < BNODES) nofs[tid] += t2;
        __syncthreads();
    }
    if (tid < BNODES) {
        int excl = nofs[tid] - ncnt[tid];
        ncur[tid] = excl;
        int node = blk * BNODES + tid;
        row_beg[node] = start + excl;
        degs[node] = (unsigned short)ncnt[tid];
    }
    __syncthreads();

    #pragma unroll
    for (int t = 0; t < 5; ++t) {
        if (preg[t] != 0xFFFFFFFFu) {
            unsigned pk = preg[t];
            int dl = (pk >> 16) & 127;
            int pos = start + atomicAdd(&ncur[dl], 1);
            csr16[pos] = (unsigned short)(pk & 0xFFFF);
        }
    }
}

// ============ fused aggregate + MFMA transform: one block per 16-node tile ============
// 4 waves each aggregate 4 nodes (8 edge-groups x 8 lanes x ushort8, 2 chains)
// into a 2 KB LDS tile; barrier; wave 0 runs h = relu(x@Ws + agg@Wn + b).
// PROJ=true fuses the layer-3 projection into p (neigh) / q (self).
// aggh global round-trip eliminated; row metadata batched (1 load + shfl per tile).

template <bool PROJ>
__global__ __launch_bounds__(256) void aggtf_kernel(
        const uint4* __restrict__ xh8, const int* __restrict__ row_beg,
        const unsigned short* __restrict__ degs,
        const unsigned short* __restrict__ csr16,
        const uint4* __restrict__ Wst, const uint4* __restrict__ Wnt,
        const float* __restrict__ b, unsigned short* __restrict__ out_bf,
        const float* __restrict__ Ws3, const float* __restrict__ Wn3,
        float* __restrict__ pout, float* __restrict__ qout) {
    __shared__ uint4 lagg[16 * 8];             // 16 nodes x 64 feats bf16
    int tid  = threadIdx.x;
    int wave = tid >> 6;
    int lane = tid & 63;
    int base = blockIdx.x * 16;

    int g   = lane >> 3;                       // edge group 0..7
    int sub = lane & 7;                        // ushort8 (8 feats) within the row

    // batched row metadata: one load for the whole tile, broadcast by shfl
    int rb_l = 0, dg_l = 0;
    if (lane < 16) { rb_l = row_beg[base + lane]; dg_l = degs[base + lane]; }

    for (int nl = wave * 4; nl < wave * 4 + 4; ++nl) {
        int beg = __shfl(rb_l, nl);
        int deg = __shfl(dg_l, nl);
        int end = beg + deg;
        float a0[8], a1[8];
        #pragma unroll
        for (int j = 0; j < 8; ++j) { a0[j] = 0.f; a1[j] = 0.f; }
        int i = beg + g;
        for (; i + 8 < end; i += 16) {         // 2 chains x 8 groups = 16 in flight
            int i0 = csr16[i];
            int i1 = csr16[i + 8];
            uint4 v0 = xh8[i0 * 8 + sub];
            uint4 v1 = xh8[i1 * 8 + sub];
            a0[0] += bflo(v0.x); a0[1] += bfhi(v0.x); a0[2] += bflo(v0.y); a0[3] += bfhi(v0.y);
            a0[4] += bflo(v0.z); a0[5] += bfhi(v0.z); a0[6] += bflo(v0.w); a0[7] += bfhi(v0.w);
            a1[0] += bflo(v1.x); a1[1] += bfhi(v1.x); a1[2] += bflo(v1.y); a1[3] += bfhi(v1.y);
            a1[4] += bflo(v1.z); a1[5] += bfhi(v1.z); a1[6] += bflo(v1.w); a1[7] += bfhi(v1.w);
        }
        if (i < end) {
            uint4 v0 = xh8[csr16[i] * 8 + sub];
            a0[0] += bflo(v0.x); a0[1] += bfhi(v0.x); a0[2] += bflo(v0.y); a0[3] += bfhi(v0.y);
            a0[4] += bflo(v0.z); a0[5] += bfhi(v0.z); a0[6] += bflo(v0.w); a0[7] += bfhi(v0.w);
        }
        float s[8];
        #pragma unroll
        for (int j = 0; j < 8; ++j) s[j] = a0[j] + a1[j];
        #pragma unroll
        for (int off = 8; off <= 32; off <<= 1)
            #pragma unroll
            for (int j = 0; j < 8; ++j)
                s[j] += __shfl_xor(s[j], off);
        if (g == 0) {
            float inv = (deg > 0) ? (1.0f / (float)deg) : 0.f;
            unsigned short o[8];
            #pragma unroll
            for (int j = 0; j < 8; ++j) o[j] = f2bf(s[j] * inv);
            uint4 pk;
            pk.x = (unsigned)o[0] | ((unsigned)o[1] << 16);
            pk.y = (unsigned)o[2] | ((unsigned)o[3] << 16);
            pk.z = (unsigned)o[4] | ((unsigned)o[5] << 16);
            pk.w = (unsigned)o[6] | ((unsigned)o[7] << 16);
            lagg[nl * 8 + sub] = pk;
        }
    }
    __syncthreads();
    if (wave != 0) return;                     // transform is one wave's work

    int lo = lane & 15, hi = lane >> 4;

    frag16 ws[2][4], wn[2][4];
    #pragma unroll
    for (int kt = 0; kt < 2; ++kt)
        #pragma unroll
        for (int jt = 0; jt < 4; ++jt) {
            int n = jt * 16 + lo;
            ws[kt][jt].u = Wst[n * 8 + kt * 4 + hi];
            wn[kt][jt].u = Wnt[n * 8 + kt * 4 + hi];
        }
    float bias_s[4];
    #pragma unroll
    for (int jt = 0; jt < 4; ++jt) bias_s[jt] = b[jt * 16 + lo];
    float w3n_s[4], w3s_s[4];
    if constexpr (PROJ) {
        #pragma unroll
        for (int jt = 0; jt < 4; ++jt) {
            w3n_s[jt] = Wn3[jt * 16 + lo];
            w3s_s[jt] = Ws3[jt * 16 + lo];
        }
    }

    frag16 ax[2], aa[2];
    #pragma unroll
    for (int kt = 0; kt < 2; ++kt) {
        ax[kt].u = xh8[(base + lo) * 8 + kt * 4 + hi];
        aa[kt].u = lagg[lo * 8 + kt * 4 + hi];
    }

    f32x4 acc[4];
    #pragma unroll
    for (int jt = 0; jt < 4; ++jt)
        acc[jt] = f32x4{bias_s[jt], bias_s[jt], bias_s[jt], bias_s[jt]};

    #pragma unroll
    for (int kt = 0; kt < 2; ++kt)
        #pragma unroll
        for (int jt = 0; jt < 4; ++jt) {
            acc[jt] = __builtin_amdgcn_mfma_f32_16x16x32_bf16(ax[kt].s, ws[kt][jt].s, acc[jt], 0, 0, 0);
            acc[jt] = __builtin_amdgcn_mfma_f32_16x16x32_bf16(aa[kt].s, wn[kt][jt].s, acc[jt], 0, 0, 0);
        }

    if constexpr (!PROJ) {
        #pragma unroll
        for (int jt = 0; jt < 4; ++jt)
            #pragma unroll
            for (int r = 0; r < 4; ++r) {
                float h = fmaxf(acc[jt][r], 0.f);
                out_bf[(base + hi * 4 + r) * F + jt * 16 + lo] = f2bf(h);
            }
    } else {
        #pragma unroll
        for (int r = 0; r < 4; ++r) {
            float pr = 0.f, qr = 0.f;
            #pragma unroll
            for (int jt = 0; jt < 4; ++jt) {
                float h = fmaxf(acc[jt][r], 0.f);
                pr += h * w3n_s[jt];
                qr += h * w3s_s[jt];
            }
            #pragma unroll
            for (int off = 1; off < 16; off <<= 1) {
                pr += __shfl_xor(pr, off);
                qr += __shfl_xor(qr, off);
            }
            if (lo == 0) {
                pout[base + hi * 4 + r] = pr;
                qout[base + hi * 4 + r] = qr;
            }
        }
    }
}

// ================ final: out = q + mean_agg(p) + b3, 16 lanes per node ================

__global__ __launch_bounds__(256) void final_kernel(
        const int* __restrict__ row_beg, const unsigned short* __restrict__ degs,
        const unsigned short* __restrict__ csr16,
        const float* __restrict__ p, const float* __restrict__ q,
        const float* __restrict__ b3, float* __restrict__ out, int n_nodes) {
    int grp = threadIdx.x >> 4;
    int ln  = threadIdx.x & 15;
    int node = blockIdx.x * 16 + grp;
    if (node >= n_nodes) return;
    int beg = row_beg[node];
    int deg = degs[node];
    int end = beg + deg;
    float s = 0.f;
    for (int i = beg + ln; i < end; i += 16) s += p[csr16[i]];
    #pragma unroll
    for (int off = 1; off < 16; off <<= 1) s += __shfl_xor(s, off);
    if (ln == 0) {
        float inv = (deg > 0) ? (1.0f / (float)deg) : 0.f;
        out[node] = q[node] + s * inv + b3[0];
    }
}

// ---------------- launch ----------------

extern "C" void kernel_launch(void* const* d_in, const int* in_sizes, int n_in,
                              void* d_out, int out_size, void* d_ws, size_t ws_size,
                              hipStream_t stream) {
    const float* x   = (const float*)d_in[0];
    const int*   src = (const int*)d_in[1];
    const int*   dst = (const int*)d_in[2];
    const float* Ws1 = (const float*)d_in[3];
    const float* Wn1 = (const float*)d_in[4];
    const float* b1  = (const float*)d_in[5];
    const float* Ws2 = (const float*)d_in[6];
    const float* Wn2 = (const float*)d_in[7];
    const float* b2  = (const float*)d_in[8];
    const float* Ws3 = (const float*)d_in[9];
    const float* Wn3 = (const float*)d_in[10];
    const float* b3  = (const float*)d_in[11];
    float* out = (float*)d_out;

    char* ws = (char*)d_ws;
    size_t cur = 0;
    auto alloc = [&](size_t bytes) -> void* {
        void* ptr = ws + cur;
        cur += (bytes + 255) & ~(size_t)255;
        return ptr;
    };

    int*            bcur     = (int*)  alloc(NB * sizeof(int));
    unsigned int*   binned   = (unsigned int*)alloc((size_t)NB * BCAP * sizeof(unsigned int));
    int*            row_beg  = (int*)  alloc((size_t)(NB * BNODES) * sizeof(int));
    unsigned short* degs     = (unsigned short*)alloc((size_t)(NB * BNODES) * sizeof(unsigned short));
    unsigned short* csr16    = (unsigned short*)alloc((size_t)NB * BCAP * sizeof(unsigned short));
    unsigned short* xh       = (unsigned short*)alloc((size_t)N_NODES * F * 2);  // bf16 x
    unsigned short* h1h      = (unsigned short*)alloc((size_t)N_NODES * F * 2);  // bf16 h1
    unsigned short* Wt       = (unsigned short*)alloc(4 * F * F * 2);            // bf16 W^T x4
    float*          p        = (float*)alloc(N_NODES * sizeof(float));
    float*          q        = (float*)alloc(N_NODES * sizeof(float));

    unsigned short* Wst1 = Wt;
    unsigned short* Wnt1 = Wt + F * F;
    unsigned short* Wst2 = Wt + 2 * F * F;
    unsigned short* Wnt2 = Wt + 3 * F * F;

    (void)hipMemsetAsync(bcur, 0, NB * sizeof(int), stream);
    scatter_prep<<<SGRID, SBLOCK, 0, stream>>>(
        src, dst, bcur, binned, Ws1, Wn1, Ws2, Wn2, Wt, (const float4*)x, (ushort4*)xh);
    bucket_build<<<NB, 512, 0, stream>>>(binned, bcur, row_beg, degs, csr16);

    // layer 1: fused aggregate + transform
    aggtf_kernel<false><<<NTILES, 256, 0, stream>>>(
        (const uint4*)xh, row_beg, degs, csr16,
        (const uint4*)Wst1, (const uint4*)Wnt1, b1, h1h,
        nullptr, nullptr, nullptr, nullptr);
    // layer 2: fused aggregate + transform + layer-3 projection
    aggtf_kernel<true><<<NTILES, 256, 0, stream>>>(
        (const uint4*)h1h, row_beg, degs, csr16,
        (const uint4*)Wst2, (const uint4*)Wnt2, b2, nullptr,
        Ws3, Wn3, p, q);
    // layer 3: aggregate scalars
    final_kernel<<<(N_NODES + 15) / 16, 256, 0, stream>>>(
        row_beg, degs, csr16, p, q, b3, out, N_NODES);
}

// Round 3
// 160.500 us; speedup vs baseline: 3.5885x; 1.0462x over previous
//
#include <hip/hip_runtime.h>

#define N_NODES 50000
#define N_EDGES 800000
#define F 64
#define NTILES (N_NODES / 16)                  // 3125
#define ATILES ((N_NODES + 31) / 32)           // 1563 blocks (32 nodes each)

#define BNODES 128                             // nodes per bucket
#define NB ((N_NODES + BNODES - 1) / BNODES)   // 391 buckets
#define BCAP 2560                              // bucket capacity (mean 2046, +25% slack)
#define EPB 2048                               // edges per scatter chunk (4/thread @512)
#define SCHUNKS ((N_EDGES + EPB - 1) / EPB)    // 391 (last chunk 1280)
#define SGRID 512                              // scatter_prep grid
#define SBLOCK 512
#define PREP_ELEMS (4 * F * F + N_NODES * 16)  // W entries + float4 groups

typedef __attribute__((ext_vector_type(8))) short short8;   // 8 bf16 (4 VGPRs)
typedef __attribute__((ext_vector_type(4))) float f32x4;    // MFMA accumulator

union frag16 { uint4 u; short8 s; };

// ---------------- bf16 helpers (storage-only; all math fp32/MFMA) ----------------

__device__ __forceinline__ float bflo(unsigned int u) {
    union { unsigned int i; float f; } c; c.i = u << 16; return c.f;
}
__device__ __forceinline__ float bfhi(unsigned int u) {
    union { unsigned int i; float f; } c; c.i = u & 0xFFFF0000u; return c.f;
}
__device__ __forceinline__ unsigned short f2bf(float f) {   // round-nearest-even
    union { float f; unsigned int i; } c; c.f = f;
    unsigned int r = c.i + 0x7FFF + ((c.i >> 16) & 1);
    return (unsigned short)(r >> 16);
}

// ============================ scatter + prep ============================
// all blocks: W fp32[k][n]->bf16 W^T[n][k] (4 mats) + x fp32->bf16 (grid-stride)
// blocks < SCHUNKS: stage EPB edges (src/dst register-cached: ONE global read),
// group by bucket in LDS, reserve global ranges, write grouped.
// packed edge: src (bits 0-15) | dst_local (bits 16-22) | bucket (bits 23-31)

__global__ __launch_bounds__(SBLOCK) void scatter_prep(
        const int* __restrict__ src, const int* __restrict__ dst,
        int* __restrict__ bcur, unsigned int* __restrict__ binned,
        const float* __restrict__ W0, const float* __restrict__ W1,
        const float* __restrict__ W2, const float* __restrict__ W3,
        unsigned short* __restrict__ Wt,
        const float4* __restrict__ xin, ushort4* __restrict__ xout) {
    __shared__ int lcnt[NB];
    __shared__ int scan[SBLOCK];
    __shared__ int gbase[NB];
    __shared__ int lcur[NB];
    __shared__ unsigned int staged[EPB];

    int tid = threadIdx.x;
    int blk = blockIdx.x;

    // ---- prep slice (independent of scatter) ----
    for (int idx = blk * SBLOCK + tid; idx < PREP_ELEMS; idx += SGRID * SBLOCK) {
        if (idx < 4 * F * F) {
            int m = idx >> 12;
            int e = idx & 4095;
            int n = e >> 6, k = e & 63;
            const float* W = (m == 0) ? W0 : (m == 1) ? W1 : (m == 2) ? W2 : W3;
            Wt[m * F * F + n * F + k] = f2bf(W[k * F + n]);
        } else {
            int i = idx - 4 * F * F;
            float4 v = xin[i];
            ushort4 o;
            o.x = f2bf(v.x); o.y = f2bf(v.y); o.z = f2bf(v.z); o.w = f2bf(v.w);
            xout[i] = o;
        }
    }

    if (blk >= SCHUNKS) return;                // block-uniform: whole block skips

    int e0 = blk * EPB;
    int e1 = min(N_EDGES, e0 + EPB);
    for (int i = tid; i < NB; i += SBLOCK) lcnt[i] = 0;
    __syncthreads();

    // register-cache the edges: one global read instead of two
    int dreg[4], sreg[4];
    #pragma unroll
    for (int t = 0; t < 4; ++t) {
        int i = e0 + tid + t * SBLOCK;
        if (i < e1) { dreg[t] = dst[i]; sreg[t] = src[i]; }
        else        { dreg[t] = -1;     sreg[t] = 0; }
    }
    #pragma unroll
    for (int t = 0; t < 4; ++t)
        if (dreg[t] >= 0) atomicAdd(&lcnt[dreg[t] >> 7], 1);
    __syncthreads();

    int v = (tid < NB) ? lcnt[tid] : 0;
    scan[tid] = v;
    __syncthreads();
    for (int off = 1; off < SBLOCK; off <<= 1) {
        int t2 = (tid >= off) ? scan[tid - off] : 0;
        __syncthreads();
        scan[tid] += t2;
        __syncthreads();
    }
    if (tid < NB) {
        int excl = scan[tid] - v;
        int resv = (v > 0) ? atomicAdd(&bcur[tid], v) : 0;
        gbase[tid] = tid * BCAP + resv - excl;
        lcur[tid] = excl;
    }
    __syncthreads();

    #pragma unroll
    for (int t = 0; t < 4; ++t) {
        if (dreg[t] >= 0) {
            int d = dreg[t];
            int b = d >> 7;
            int dl = d & 127;
            int posl = atomicAdd(&lcur[b], 1);
            staged[posl] = (unsigned)sreg[t] | ((unsigned)dl << 16) | ((unsigned)b << 23);
        }
    }
    __syncthreads();

    int cnt = e1 - e0;
    for (int i = tid; i < cnt; i += SBLOCK) {
        unsigned pk = staged[i];
        binned[gbase[pk >> 23] + i] = pk;      // grouped -> mostly coalesced
    }
}

// ============================ bucket CSR build ============================
// per bucket: node counts + local scan -> row_beg/degs/csr16 (binned reg-cached)

__global__ __launch_bounds__(512) void bucket_build(
        const unsigned int* __restrict__ binned, const int* __restrict__ bcur,
        int* __restrict__ row_beg, unsigned short* __restrict__ degs,
        unsigned short* __restrict__ csr16) {
    __shared__ int ncnt[BNODES];
    __shared__ int nofs[BNODES];
    __shared__ int ncur[BNODES];
    int blk = blockIdx.x;
    int tid = threadIdx.x;
    int start = blk * BCAP;
    int cnt = min(bcur[blk], BCAP);

    for (int i = tid; i < BNODES; i += 512) ncnt[i] = 0;
    __syncthreads();

    // register-cache bucket entries: one global read instead of two
    unsigned preg[5];
    #pragma unroll
    for (int t = 0; t < 5; ++t) {
        int i = tid + t * 512;
        preg[t] = (i < cnt) ? binned[start + i] : 0xFFFFFFFFu;
    }
    #pragma unroll
    for (int t = 0; t < 5; ++t)
        if (preg[t] != 0xFFFFFFFFu)
            atomicAdd(&ncnt[(preg[t] >> 16) & 127], 1);
    __syncthreads();

    if (tid < BNODES) nofs[tid] = ncnt[tid];
    __syncthreads();
    for (int off = 1; off < BNODES; off <<= 1) {
        int t2 = (tid >= off && tid < BNODES) ? nofs[tid - off] : 0;
        __syncthreads();
        if (tid < BNODES) nofs[tid] += t2;
        __syncthreads();
    }
    if (tid < BNODES) {
        int excl = nofs[tid] - ncnt[tid];
        ncur[tid] = excl;
        int node = blk * BNODES + tid;
        row_beg[node] = start + excl;
        degs[node] = (unsigned short)ncnt[tid];
    }
    __syncthreads();

    #pragma unroll
    for (int t = 0; t < 5; ++t) {
        if (preg[t] != 0xFFFFFFFFu) {
            unsigned pk = preg[t];
            int dl = (pk >> 16) & 127;
            int pos = start + atomicAdd(&ncur[dl], 1);
            csr16[pos] = (unsigned short)(pk & 0xFFFF);
        }
    }
}

// ============ fused aggregate + MFMA transform: one block per 32-node tile ============
// Aggregation: 8 lanes per node x 8 nodes per wave, NO cross-lane reduce.
// Each lane owns a ushort8 feature slice (16B) and loops the node's edge list
// (2-edge unroll -> 16 outstanding 128B gathers/wave). Degree-matched: at mean
// deg 16 this halves lane-ops vs the 8-group+shfl-reduce layout and removes
// 1.2M ds_bpermute per layer.
// Then barrier; waves 0,1 each run the MFMA transform for one 16-node tile.
// PROJ=true fuses the layer-3 projection into p (neigh) / q (self).

template <bool PROJ>
__global__ __launch_bounds__(256) void aggtf_kernel(
        const uint4* __restrict__ xh8, const int* __restrict__ row_beg,
        const unsigned short* __restrict__ degs,
        const unsigned short* __restrict__ csr16,
        const uint4* __restrict__ Wst, const uint4* __restrict__ Wnt,
        const float* __restrict__ b, unsigned short* __restrict__ out_bf,
        const float* __restrict__ Ws3, const float* __restrict__ Wn3,
        float* __restrict__ pout, float* __restrict__ qout) {
    __shared__ uint4 lagg[32 * 8];             // 32 nodes x 64 feats bf16 (4 KB)
    int tid  = threadIdx.x;
    int wave = tid >> 6;
    int lane = tid & 63;
    int base = blockIdx.x * 32;

    int nsub = lane >> 3;                      // node within wave's 8
    int sub  = lane & 7;                       // ushort8 feature slice
    int node_l = wave * 8 + nsub;              // 0..31 within block

    // batched row metadata: lanes 0..31 load all 32 nodes, broadcast by shfl
    int rb_l = 0, dg_l = 0;
    if (lane < 32 && base + lane < N_NODES) {
        rb_l = row_beg[base + lane];
        dg_l = degs[base + lane];
    }
    int beg = __shfl(rb_l, node_l);
    int deg = __shfl(dg_l, node_l);
    int end = beg + deg;

    float a0[8], a1[8];
    #pragma unroll
    for (int j = 0; j < 8; ++j) { a0[j] = 0.f; a1[j] = 0.f; }

    int i = beg;
    for (; i + 1 < end; i += 2) {              // 2 chains: 16 gathers in flight/wave
        int i0 = csr16[i];
        int i1 = csr16[i + 1];
        uint4 v0 = xh8[i0 * 8 + sub];
        uint4 v1 = xh8[i1 * 8 + sub];
        a0[0] += bflo(v0.x); a0[1] += bfhi(v0.x); a0[2] += bflo(v0.y); a0[3] += bfhi(v0.y);
        a0[4] += bflo(v0.z); a0[5] += bfhi(v0.z); a0[6] += bflo(v0.w); a0[7] += bfhi(v0.w);
        a1[0] += bflo(v1.x); a1[1] += bfhi(v1.x); a1[2] += bflo(v1.y); a1[3] += bfhi(v1.y);
        a1[4] += bflo(v1.z); a1[5] += bfhi(v1.z); a1[6] += bflo(v1.w); a1[7] += bfhi(v1.w);
    }
    if (i < end) {
        uint4 v0 = xh8[csr16[i] * 8 + sub];
        a0[0] += bflo(v0.x); a0[1] += bfhi(v0.x); a0[2] += bflo(v0.y); a0[3] += bfhi(v0.y);
        a0[4] += bflo(v0.z); a0[5] += bfhi(v0.z); a0[6] += bflo(v0.w); a0[7] += bfhi(v0.w);
    }
    {
        float inv = (deg > 0) ? (1.0f / (float)deg) : 0.f;
        unsigned short o[8];
        #pragma unroll
        for (int j = 0; j < 8; ++j) o[j] = f2bf((a0[j] + a1[j]) * inv);
        uint4 pk;
        pk.x = (unsigned)o[0] | ((unsigned)o[1] << 16);
        pk.y = (unsigned)o[2] | ((unsigned)o[3] << 16);
        pk.z = (unsigned)o[4] | ((unsigned)o[5] << 16);
        pk.w = (unsigned)o[6] | ((unsigned)o[7] << 16);
        lagg[node_l * 8 + sub] = pk;           // each lane writes its slice
    }
    __syncthreads();

    if (wave >= 2) return;                     // 2 waves transform 2 tiles
    int tbase = base + wave * 16;
    if (tbase + 16 > N_NODES) return;          // N_NODES % 16 == 0: all-or-nothing

    int lo = lane & 15, hi = lane >> 4;

    frag16 ws[2][4], wn[2][4];
    #pragma unroll
    for (int kt = 0; kt < 2; ++kt)
        #pragma unroll
        for (int jt = 0; jt < 4; ++jt) {
            int n = jt * 16 + lo;
            ws[kt][jt].u = Wst[n * 8 + kt * 4 + hi];
            wn[kt][jt].u = Wnt[n * 8 + kt * 4 + hi];
        }
    float bias_s[4];
    #pragma unroll
    for (int jt = 0; jt < 4; ++jt) bias_s[jt] = b[jt * 16 + lo];
    float w3n_s[4], w3s_s[4];
    if constexpr (PROJ) {
        #pragma unroll
        for (int jt = 0; jt < 4; ++jt) {
            w3n_s[jt] = Wn3[jt * 16 + lo];
            w3s_s[jt] = Ws3[jt * 16 + lo];
        }
    }

    frag16 ax[2], aa[2];
    #pragma unroll
    for (int kt = 0; kt < 2; ++kt) {
        ax[kt].u = xh8[(tbase + lo) * 8 + kt * 4 + hi];
        aa[kt].u = lagg[(wave * 16 + lo) * 8 + kt * 4 + hi];
    }

    f32x4 acc[4];
    #pragma unroll
    for (int jt = 0; jt < 4; ++jt)
        acc[jt] = f32x4{bias_s[jt], bias_s[jt], bias_s[jt], bias_s[jt]};

    #pragma unroll
    for (int kt = 0; kt < 2; ++kt)
        #pragma unroll
        for (int jt = 0; jt < 4; ++jt) {
            acc[jt] = __builtin_amdgcn_mfma_f32_16x16x32_bf16(ax[kt].s, ws[kt][jt].s, acc[jt], 0, 0, 0);
            acc[jt] = __builtin_amdgcn_mfma_f32_16x16x32_bf16(aa[kt].s, wn[kt][jt].s, acc[jt], 0, 0, 0);
        }

    if constexpr (!PROJ) {
        #pragma unroll
        for (int jt = 0; jt < 4; ++jt)
            #pragma unroll
            for (int r = 0; r < 4; ++r) {
                float h = fmaxf(acc[jt][r], 0.f);
                out_bf[(tbase + hi * 4 + r) * F + jt * 16 + lo] = f2bf(h);
            }
    } else {
        #pragma unroll
        for (int r = 0; r < 4; ++r) {
            float pr = 0.f, qr = 0.f;
            #pragma unroll
            for (int jt = 0; jt < 4; ++jt) {
                float h = fmaxf(acc[jt][r], 0.f);
                pr += h * w3n_s[jt];
                qr += h * w3s_s[jt];
            }
            #pragma unroll
            for (int off = 1; off < 16; off <<= 1) {
                pr += __shfl_xor(pr, off);
                qr += __shfl_xor(qr, off);
            }
            if (lo == 0) {
                pout[tbase + hi * 4 + r] = pr;
                qout[tbase + hi * 4 + r] = qr;
            }
        }
    }
}

// ================ final: out = q + mean_agg(p) + b3, 16 lanes per node ================

__global__ __launch_bounds__(256) void final_kernel(
        const int* __restrict__ row_beg, const unsigned short* __restrict__ degs,
        const unsigned short* __restrict__ csr16,
        const float* __restrict__ p, const float* __restrict__ q,
        const float* __restrict__ b3, float* __restrict__ out, int n_nodes) {
    int grp = threadIdx.x >> 4;
    int ln  = threadIdx.x & 15;
    int node = blockIdx.x * 16 + grp;
    if (node >= n_nodes) return;
    int beg = row_beg[node];
    int deg = degs[node];
    int end = beg + deg;
    float s = 0.f;
    for (int i = beg + ln; i < end; i += 16) s += p[csr16[i]];
    #pragma unroll
    for (int off = 1; off < 16; off <<= 1) s += __shfl_xor(s, off);
    if (ln == 0) {
        float inv = (deg > 0) ? (1.0f / (float)deg) : 0.f;
        out[node] = q[node] + s * inv + b3[0];
    }
}

// ---------------- launch ----------------

extern "C" void kernel_launch(void* const* d_in, const int* in_sizes, int n_in,
                              void* d_out, int out_size, void* d_ws, size_t ws_size,
                              hipStream_t stream) {
    const float* x   = (const float*)d_in[0];
    const int*   src = (const int*)d_in[1];
    const int*   dst = (const int*)d_in[2];
    const float* Ws1 = (const float*)d_in[3];
    const float* Wn1 = (const float*)d_in[4];
    const float* b1  = (const float*)d_in[5];
    const float* Ws2 = (const float*)d_in[6];
    const float* Wn2 = (const float*)d_in[7];
    const float* b2  = (const float*)d_in[8];
    const float* Ws3 = (const float*)d_in[9];
    const float* Wn3 = (const float*)d_in[10];
    const float* b3  = (const float*)d_in[11];
    float* out = (float*)d_out;

    char* ws = (char*)d_ws;
    size_t cur = 0;
    auto alloc = [&](size_t bytes) -> void* {
        void* ptr = ws + cur;
        cur += (bytes + 255) & ~(size_t)255;
        return ptr;
    };

    int*            bcur     = (int*)  alloc(NB * sizeof(int));
    unsigned int*   binned   = (unsigned int*)alloc((size_t)NB * BCAP * sizeof(unsigned int));
    int*            row_beg  = (int*)  alloc((size_t)(NB * BNODES) * sizeof(int));
    unsigned short* degs     = (unsigned short*)alloc((size_t)(NB * BNODES) * sizeof(unsigned short));
    unsigned short* csr16    = (unsigned short*)alloc((size_t)NB * BCAP * sizeof(unsigned short));
    unsigned short* xh       = (unsigned short*)alloc((size_t)N_NODES * F * 2);  // bf16 x
    unsigned short* h1h      = (unsigned short*)alloc((size_t)N_NODES * F * 2);  // bf16 h1
    unsigned short* Wt       = (unsigned short*)alloc(4 * F * F * 2);            // bf16 W^T x4
    float*          p        = (float*)alloc(N_NODES * sizeof(float));
    float*          q        = (float*)alloc(N_NODES * sizeof(float));

    unsigned short* Wst1 = Wt;
    unsigned short* Wnt1 = Wt + F * F;
    unsigned short* Wst2 = Wt + 2 * F * F;
    unsigned short* Wnt2 = Wt + 3 * F * F;

    (void)hipMemsetAsync(bcur, 0, NB * sizeof(int), stream);
    scatter_prep<<<SGRID, SBLOCK, 0, stream>>>(
        src, dst, bcur, binned, Ws1, Wn1, Ws2, Wn2, Wt, (const float4*)x, (ushort4*)xh);
    bucket_build<<<NB, 512, 0, stream>>>(binned, bcur, row_beg, degs, csr16);

    // layer 1: fused aggregate + transform
    aggtf_kernel<false><<<ATILES, 256, 0, stream>>>(
        (const uint4*)xh, row_beg, degs, csr16,
        (const uint4*)Wst1, (const uint4*)Wnt1, b1, h1h,
        nullptr, nullptr, nullptr, nullptr);
    // layer 2: fused aggregate + transform + layer-3 projection
    aggtf_kernel<true><<<ATILES, 256, 0, stream>>>(
        (const uint4*)h1h, row_beg, degs, csr16,
        (const uint4*)Wst2, (const uint4*)Wnt2, b2, nullptr,
        Ws3, Wn3, p, q);
    // layer 3: aggregate scalars
    final_kernel<<<(N_NODES + 15) / 16, 256, 0, stream>>>(
        row_beg, degs, csr16, p, q, b3, out, N_NODES);
}

// Round 4
// 155.888 us; speedup vs baseline: 3.6947x; 1.0296x over previous
//
#include <hip/hip_runtime.h>

#define N_NODES 50000
#define N_EDGES 800000
#define F 64
#define NTILES (N_NODES / 16)                  // 3125
#define ATILES ((N_NODES + 31) / 32)           // 1563 blocks (32 nodes each)

#define BNODES 128                             // nodes per bucket
#define NB ((N_NODES + BNODES - 1) / BNODES)   // 391 buckets
#define BCAP 2560                              // bucket capacity (mean 2046, +25% slack)
#define EPB 2048                               // edges per scatter chunk (4/thread @512)
#define SCHUNKS ((N_EDGES + EPB - 1) / EPB)    // 391 (last chunk 1280)
#define SGRID 512                              // scatter_prep grid
#define SBLOCK 512
#define PREP_ELEMS (4 * F * F + N_NODES * 16)  // W entries + float4 groups

typedef __attribute__((ext_vector_type(8))) short short8;   // 8 bf16 (4 VGPRs)
typedef __attribute__((ext_vector_type(4))) float f32x4;    // MFMA accumulator

union frag16 { uint4 u; short8 s; };

// ---------------- bf16 helpers (storage-only; all math fp32/MFMA) ----------------

__device__ __forceinline__ float bflo(unsigned int u) {
    union { unsigned int i; float f; } c; c.i = u << 16; return c.f;
}
__device__ __forceinline__ float bfhi(unsigned int u) {
    union { unsigned int i; float f; } c; c.i = u & 0xFFFF0000u; return c.f;
}
__device__ __forceinline__ unsigned short f2bf(float f) {   // round-nearest-even
    union { float f; unsigned int i; } c; c.f = f;
    unsigned int r = c.i + 0x7FFF + ((c.i >> 16) & 1);
    return (unsigned short)(r >> 16);
}

__device__ __forceinline__ void acc8(float* a, uint4 v) {
    a[0] += bflo(v.x); a[1] += bfhi(v.x);
    a[2] += bflo(v.y); a[3] += bfhi(v.y);
    a[4] += bflo(v.z); a[5] += bfhi(v.z);
    a[6] += bflo(v.w); a[7] += bfhi(v.w);
}

// ============================ scatter + prep ============================
// all blocks: W fp32[k][n]->bf16 W^T[n][k] (4 mats) + x fp32->bf16 (grid-stride)
// blocks < SCHUNKS: stage EPB edges (src/dst register-cached: ONE global read),
// group by bucket in LDS, reserve global ranges, write grouped.
// packed edge: src (bits 0-15) | dst_local (bits 16-22) | bucket (bits 23-31)

__global__ __launch_bounds__(SBLOCK) void scatter_prep(
        const int* __restrict__ src, const int* __restrict__ dst,
        int* __restrict__ bcur, unsigned int* __restrict__ binned,
        const float* __restrict__ W0, const float* __restrict__ W1,
        const float* __restrict__ W2, const float* __restrict__ W3,
        unsigned short* __restrict__ Wt,
        const float4* __restrict__ xin, ushort4* __restrict__ xout) {
    __shared__ int lcnt[NB];
    __shared__ int scan[SBLOCK];
    __shared__ int gbase[NB];
    __shared__ int lcur[NB];
    __shared__ unsigned int staged[EPB];

    int tid = threadIdx.x;
    int blk = blockIdx.x;

    // ---- prep slice (independent of scatter) ----
    for (int idx = blk * SBLOCK + tid; idx < PREP_ELEMS; idx += SGRID * SBLOCK) {
        if (idx < 4 * F * F) {
            int m = idx >> 12;
            int e = idx & 4095;
            int n = e >> 6, k = e & 63;
            const float* W = (m == 0) ? W0 : (m == 1) ? W1 : (m == 2) ? W2 : W3;
            Wt[m * F * F + n * F + k] = f2bf(W[k * F + n]);
        } else {
            int i = idx - 4 * F * F;
            float4 v = xin[i];
            ushort4 o;
            o.x = f2bf(v.x); o.y = f2bf(v.y); o.z = f2bf(v.z); o.w = f2bf(v.w);
            xout[i] = o;
        }
    }

    if (blk >= SCHUNKS) return;                // block-uniform: whole block skips

    int e0 = blk * EPB;
    int e1 = min(N_EDGES, e0 + EPB);
    for (int i = tid; i < NB; i += SBLOCK) lcnt[i] = 0;
    __syncthreads();

    // register-cache the edges: one global read instead of two
    int dreg[4], sreg[4];
    #pragma unroll
    for (int t = 0; t < 4; ++t) {
        int i = e0 + tid + t * SBLOCK;
        if (i < e1) { dreg[t] = dst[i]; sreg[t] = src[i]; }
        else        { dreg[t] = -1;     sreg[t] = 0; }
    }
    #pragma unroll
    for (int t = 0; t < 4; ++t)
        if (dreg[t] >= 0) atomicAdd(&lcnt[dreg[t] >> 7], 1);
    __syncthreads();

    int v = (tid < NB) ? lcnt[tid] : 0;
    scan[tid] = v;
    __syncthreads();
    for (int off = 1; off < SBLOCK; off <<= 1) {
        int t2 = (tid >= off) ? scan[tid - off] : 0;
        __syncthreads();
        scan[tid] += t2;
        __syncthreads();
    }
    if (tid < NB) {
        int excl = scan[tid] - v;
        int resv = (v > 0) ? atomicAdd(&bcur[tid], v) : 0;
        gbase[tid] = tid * BCAP + resv - excl;
        lcur[tid] = excl;
    }
    __syncthreads();

    #pragma unroll
    for (int t = 0; t < 4; ++t) {
        if (dreg[t] >= 0) {
            int d = dreg[t];
            int b = d >> 7;
            int dl = d & 127;
            int posl = atomicAdd(&lcur[b], 1);
            staged[posl] = (unsigned)sreg[t] | ((unsigned)dl << 16) | ((unsigned)b << 23);
        }
    }
    __syncthreads();

    int cnt = e1 - e0;
    for (int i = tid; i < cnt; i += SBLOCK) {
        unsigned pk = staged[i];
        binned[gbase[pk >> 23] + i] = pk;      // grouped -> mostly coalesced
    }
}

// ============================ bucket CSR build ============================
// per bucket: node counts + local scan -> row_beg/degs/csr16 (binned reg-cached)

__global__ __launch_bounds__(512) void bucket_build(
        const unsigned int* __restrict__ binned, const int* __restrict__ bcur,
        int* __restrict__ row_beg, unsigned short* __restrict__ degs,
        unsigned short* __restrict__ csr16) {
    __shared__ int ncnt[BNODES];
    __shared__ int nofs[BNODES];
    __shared__ int ncur[BNODES];
    int blk = blockIdx.x;
    int tid = threadIdx.x;
    int start = blk * BCAP;
    int cnt = min(bcur[blk], BCAP);

    for (int i = tid; i < BNODES; i += 512) ncnt[i] = 0;
    __syncthreads();

    // register-cache bucket entries: one global read instead of two
    unsigned preg[5];
    #pragma unroll
    for (int t = 0; t < 5; ++t) {
        int i = tid + t * 512;
        preg[t] = (i < cnt) ? binned[start + i] : 0xFFFFFFFFu;
    }
    #pragma unroll
    for (int t = 0; t < 5; ++t)
        if (preg[t] != 0xFFFFFFFFu)
            atomicAdd(&ncnt[(preg[t] >> 16) & 127], 1);
    __syncthreads();

    if (tid < BNODES) nofs[tid] = ncnt[tid];
    __syncthreads();
    for (int off = 1; off < BNODES; off <<= 1) {
        int t2 = (tid >= off && tid < BNODES) ? nofs[tid - off] : 0;
        __syncthreads();
        if (tid < BNODES) nofs[tid] += t2;
        __syncthreads();
    }
    if (tid < BNODES) {
        int excl = nofs[tid] - ncnt[tid];
        ncur[tid] = excl;
        int node = blk * BNODES + tid;
        row_beg[node] = start + excl;
        degs[node] = (unsigned short)ncnt[tid];
    }
    __syncthreads();

    #pragma unroll
    for (int t = 0; t < 5; ++t) {
        if (preg[t] != 0xFFFFFFFFu) {
            unsigned pk = preg[t];
            int dl = (pk >> 16) & 127;
            int pos = start + atomicAdd(&ncur[dl], 1);
            csr16[pos] = (unsigned short)(pk & 0xFFFF);
        }
    }
}

// ============ fused aggregate + MFMA transform: one block per 32-node tile ============
// Aggregation: 8 lanes per node x 8 nodes per wave, NO cross-lane reduce.
// Edge loop is 4-deep unrolled with ONE-QUAD-AHEAD index prefetch: csr16 indices
// for quad k+1 issue before the gathers of quad k are consumed, breaking the
// dependent csr16->xh8 two-hop latency chain. Tail handled by a clamped,
// predicated quad (no serial remainder).
// lagg is XOR-swizzled (col ^= row&7): the transform's 128B-stride ds_read_b128
// was a 16-way bank conflict, now 2-way (free).
// Then barrier; waves 0,1 each run the MFMA transform for one 16-node tile.
// PROJ=true fuses the layer-3 projection into p (neigh) / q (self).

template <bool PROJ>
__global__ __launch_bounds__(256) void aggtf_kernel(
        const uint4* __restrict__ xh8, const int* __restrict__ row_beg,
        const unsigned short* __restrict__ degs,
        const unsigned short* __restrict__ csr16,
        const uint4* __restrict__ Wst, const uint4* __restrict__ Wnt,
        const float* __restrict__ b, unsigned short* __restrict__ out_bf,
        const float* __restrict__ Ws3, const float* __restrict__ Wn3,
        float* __restrict__ pout, float* __restrict__ qout) {
    __shared__ uint4 lagg[32 * 8];             // 32 nodes x 64 feats bf16 (4 KB)
    int tid  = threadIdx.x;
    int wave = tid >> 6;
    int lane = tid & 63;
    int base = blockIdx.x * 32;

    int nsub = lane >> 3;                      // node within wave's 8
    int sub  = lane & 7;                       // ushort8 feature slice
    int node_l = wave * 8 + nsub;              // 0..31 within block

    // batched row metadata: lanes 0..31 load all 32 nodes, broadcast by shfl
    int rb_l = 0, dg_l = 0;
    if (lane < 32 && base + lane < N_NODES) {
        rb_l = row_beg[base + lane];
        dg_l = degs[base + lane];
    }
    int beg = __shfl(rb_l, node_l);
    int deg = __shfl(dg_l, node_l);
    int end = beg + deg;

    float a0[8], a1[8], a2[8], a3[8];
    #pragma unroll
    for (int j = 0; j < 8; ++j) { a0[j] = 0.f; a1[j] = 0.f; a2[j] = 0.f; a3[j] = 0.f; }

    int i = beg;
    int c0 = 0, c1 = 0, c2 = 0, c3 = 0;
    if (i < end) {                             // prefetch first quad (clamped)
        int el = end - 1;
        c0 = csr16[i];
        c1 = csr16[min(i + 1, el)];
        c2 = csr16[min(i + 2, el)];
        c3 = csr16[min(i + 3, el)];
    }
    while (i + 4 < end) {                      // full quad + next-quad prefetch
        int ni = i + 4;
        int el = end - 1;
        int n0 = csr16[ni];
        int n1 = csr16[min(ni + 1, el)];
        int n2 = csr16[min(ni + 2, el)];
        int n3 = csr16[min(ni + 3, el)];
        uint4 v0 = xh8[c0 * 8 + sub];
        uint4 v1 = xh8[c1 * 8 + sub];
        uint4 v2 = xh8[c2 * 8 + sub];
        uint4 v3 = xh8[c3 * 8 + sub];
        acc8(a0, v0); acc8(a1, v1); acc8(a2, v2); acc8(a3, v3);
        c0 = n0; c1 = n1; c2 = n2; c3 = n3;
        i = ni;
    }
    if (i < end) {                             // tail quad: clamped + predicated
        uint4 v0 = xh8[c0 * 8 + sub];
        uint4 v1 = xh8[c1 * 8 + sub];
        uint4 v2 = xh8[c2 * 8 + sub];
        uint4 v3 = xh8[c3 * 8 + sub];
        acc8(a0, v0);
        if (i + 1 < end) acc8(a1, v1);
        if (i + 2 < end) acc8(a2, v2);
        if (i + 3 < end) acc8(a3, v3);
    }
    {
        float inv = (deg > 0) ? (1.0f / (float)deg) : 0.f;
        unsigned short o[8];
        #pragma unroll
        for (int j = 0; j < 8; ++j)
            o[j] = f2bf(((a0[j] + a1[j]) + (a2[j] + a3[j])) * inv);
        uint4 pk;
        pk.x = (unsigned)o[0] | ((unsigned)o[1] << 16);
        pk.y = (unsigned)o[2] | ((unsigned)o[3] << 16);
        pk.z = (unsigned)o[4] | ((unsigned)o[5] << 16);
        pk.w = (unsigned)o[6] | ((unsigned)o[7] << 16);
        lagg[node_l * 8 + (sub ^ (node_l & 7))] = pk;   // XOR-swizzled slice
    }
    __syncthreads();

    if (wave >= 2) return;                     // 2 waves transform 2 tiles
    int tbase = base + wave * 16;
    if (tbase + 16 > N_NODES) return;          // N_NODES % 16 == 0: all-or-nothing

    int lo = lane & 15, hi = lane >> 4;

    frag16 ws[2][4], wn[2][4];
    #pragma unroll
    for (int kt = 0; kt < 2; ++kt)
        #pragma unroll
        for (int jt = 0; jt < 4; ++jt) {
            int n = jt * 16 + lo;
            ws[kt][jt].u = Wst[n * 8 + kt * 4 + hi];
            wn[kt][jt].u = Wnt[n * 8 + kt * 4 + hi];
        }
    float bias_s[4];
    #pragma unroll
    for (int jt = 0; jt < 4; ++jt) bias_s[jt] = b[jt * 16 + lo];
    float w3n_s[4], w3s_s[4];
    if constexpr (PROJ) {
        #pragma unroll
        for (int jt = 0; jt < 4; ++jt) {
            w3n_s[jt] = Wn3[jt * 16 + lo];
            w3s_s[jt] = Ws3[jt * 16 + lo];
        }
    }

    frag16 ax[2], aa[2];
    #pragma unroll
    for (int kt = 0; kt < 2; ++kt) {
        int row = wave * 16 + lo;
        ax[kt].u = xh8[(tbase + lo) * 8 + kt * 4 + hi];
        aa[kt].u = lagg[row * 8 + ((kt * 4 + hi) ^ (row & 7))];   // matching swizzle
    }

    f32x4 acc[4];
    #pragma unroll
    for (int jt = 0; jt < 4; ++jt)
        acc[jt] = f32x4{bias_s[jt], bias_s[jt], bias_s[jt], bias_s[jt]};

    #pragma unroll
    for (int kt = 0; kt < 2; ++kt)
        #pragma unroll
        for (int jt = 0; jt < 4; ++jt) {
            acc[jt] = __builtin_amdgcn_mfma_f32_16x16x32_bf16(ax[kt].s, ws[kt][jt].s, acc[jt], 0, 0, 0);
            acc[jt] = __builtin_amdgcn_mfma_f32_16x16x32_bf16(aa[kt].s, wn[kt][jt].s, acc[jt], 0, 0, 0);
        }

    if constexpr (!PROJ) {
        #pragma unroll
        for (int jt = 0; jt < 4; ++jt)
            #pragma unroll
            for (int r = 0; r < 4; ++r) {
                float h = fmaxf(acc[jt][r], 0.f);
                out_bf[(tbase + hi * 4 + r) * F + jt * 16 + lo] = f2bf(h);
            }
    } else {
        #pragma unroll
        for (int r = 0; r < 4; ++r) {
            float pr = 0.f, qr = 0.f;
            #pragma unroll
            for (int jt = 0; jt < 4; ++jt) {
                float h = fmaxf(acc[jt][r], 0.f);
                pr += h * w3n_s[jt];
                qr += h * w3s_s[jt];
            }
            #pragma unroll
            for (int off = 1; off < 16; off <<= 1) {
                pr += __shfl_xor(pr, off);
                qr += __shfl_xor(qr, off);
            }
            if (lo == 0) {
                pout[tbase + hi * 4 + r] = pr;
                qout[tbase + hi * 4 + r] = qr;
            }
        }
    }
}

// ================ final: out = q + mean_agg(p) + b3, 16 lanes per node ================

__global__ __launch_bounds__(256) void final_kernel(
        const int* __restrict__ row_beg, const unsigned short* __restrict__ degs,
        const unsigned short* __restrict__ csr16,
        const float* __restrict__ p, const float* __restrict__ q,
        const float* __restrict__ b3, float* __restrict__ out, int n_nodes) {
    int grp = threadIdx.x >> 4;
    int ln  = threadIdx.x & 15;
    int node = blockIdx.x * 16 + grp;
    if (node >= n_nodes) return;
    int beg = row_beg[node];
    int deg = degs[node];
    int end = beg + deg;
    float s = 0.f;
    for (int i = beg + ln; i < end; i += 16) s += p[csr16[i]];
    #pragma unroll
    for (int off = 1; off < 16; off <<= 1) s += __shfl_xor(s, off);
    if (ln == 0) {
        float inv = (deg > 0) ? (1.0f / (float)deg) : 0.f;
        out[node] = q[node] + s * inv + b3[0];
    }
}

// ---------------- launch ----------------

extern "C" void kernel_launch(void* const* d_in, const int* in_sizes, int n_in,
                              void* d_out, int out_size, void* d_ws, size_t ws_size,
                              hipStream_t stream) {
    const float* x   = (const float*)d_in[0];
    const int*   src = (const int*)d_in[1];
    const int*   dst = (const int*)d_in[2];
    const float* Ws1 = (const float*)d_in[3];
    const float* Wn1 = (const float*)d_in[4];
    const float* b1  = (const float*)d_in[5];
    const float* Ws2 = (const float*)d_in[6];
    const float* Wn2 = (const float*)d_in[7];
    const float* b2  = (const float*)d_in[8];
    const float* Ws3 = (const float*)d_in[9];
    const float* Wn3 = (const float*)d_in[10];
    const float* b3  = (const float*)d_in[11];
    float* out = (float*)d_out;

    char* ws = (char*)d_ws;
    size_t cur = 0;
    auto alloc = [&](size_t bytes) -> void* {
        void* ptr = ws + cur;
        cur += (bytes + 255) & ~(size_t)255;
        return ptr;
    };

    int*            bcur     = (int*)  alloc(NB * sizeof(int));
    unsigned int*   binned   = (unsigned int*)alloc((size_t)NB * BCAP * sizeof(unsigned int));
    int*            row_beg  = (int*)  alloc((size_t)(NB * BNODES) * sizeof(int));
    unsigned short* degs     = (unsigned short*)alloc((size_t)(NB * BNODES) * sizeof(unsigned short));
    unsigned short* csr16    = (unsigned short*)alloc((size_t)NB * BCAP * sizeof(unsigned short));
    unsigned short* xh       = (unsigned short*)alloc((size_t)N_NODES * F * 2);  // bf16 x
    unsigned short* h1h      = (unsigned short*)alloc((size_t)N_NODES * F * 2);  // bf16 h1
    unsigned short* Wt       = (unsigned short*)alloc(4 * F * F * 2);            // bf16 W^T x4
    float*          p        = (float*)alloc(N_NODES * sizeof(float));
    float*          q        = (float*)alloc(N_NODES * sizeof(float));

    unsigned short* Wst1 = Wt;
    unsigned short* Wnt1 = Wt + F * F;
    unsigned short* Wst2 = Wt + 2 * F * F;
    unsigned short* Wnt2 = Wt + 3 * F * F;

    (void)hipMemsetAsync(bcur, 0, NB * sizeof(int), stream);
    scatter_prep<<<SGRID, SBLOCK, 0, stream>>>(
        src, dst, bcur, binned, Ws1, Wn1, Ws2, Wn2, Wt, (const float4*)x, (ushort4*)xh);
    bucket_build<<<NB, 512, 0, stream>>>(binned, bcur, row_beg, degs, csr16);

    // layer 1: fused aggregate + transform
    aggtf_kernel<false><<<ATILES, 256, 0, stream>>>(
        (const uint4*)xh, row_beg, degs, csr16,
        (const uint4*)Wst1, (const uint4*)Wnt1, b1, h1h,
        nullptr, nullptr, nullptr, nullptr);
    // layer 2: fused aggregate + transform + layer-3 projection
    aggtf_kernel<true><<<ATILES, 256, 0, stream>>>(
        (const uint4*)h1h, row_beg, degs, csr16,
        (const uint4*)Wst2, (const uint4*)Wnt2, b2, nullptr,
        Ws3, Wn3, p, q);
    // layer 3: aggregate scalars
    final_kernel<<<(N_NODES + 15) / 16, 256, 0, stream>>>(
        row_beg, degs, csr16, p, q, b3, out, N_NODES);
}

// Round 5
// 152.968 us; speedup vs baseline: 3.7652x; 1.0191x over previous
//
#include <hip/hip_runtime.h>

#define N_NODES 50000
#define N_EDGES 800000
#define F 64
#define NTILES (N_NODES / 16)                  // 3125
#define ATILES ((N_NODES + 31) / 32)           // 1563 blocks (32 nodes each)

#define BNODES 128                             // nodes per bucket
#define NB ((N_NODES + BNODES - 1) / BNODES)   // 391 buckets
#define BCAP 2560                              // bucket capacity (mean 2046, +25% slack)
#define EPB 2048                               // edges per scatter chunk (4/thread @512)
#define SCHUNKS ((N_EDGES + EPB - 1) / EPB)    // 391 (last chunk 1280)
#define SGRID 512                              // scatter_prep grid
#define SBLOCK 512
#define PREP_ELEMS (4 * F * F + N_NODES * 16)  // W entries + float4 groups

typedef __attribute__((ext_vector_type(8))) short short8;   // 8 bf16 (4 VGPRs)
typedef __attribute__((ext_vector_type(4))) float f32x4;    // MFMA accumulator

union frag16 { uint4 u; short8 s; };

// ---------------- bf16 helpers (storage-only; all math fp32/MFMA) ----------------

__device__ __forceinline__ float bflo(unsigned int u) {
    union { unsigned int i; float f; } c; c.i = u << 16; return c.f;
}
__device__ __forceinline__ float bfhi(unsigned int u) {
    union { unsigned int i; float f; } c; c.i = u & 0xFFFF0000u; return c.f;
}
__device__ __forceinline__ unsigned short f2bf(float f) {   // round-nearest-even
    union { float f; unsigned int i; } c; c.f = f;
    unsigned int r = c.i + 0x7FFF + ((c.i >> 16) & 1);
    return (unsigned short)(r >> 16);
}

__device__ __forceinline__ void acc8(float* a, uint4 v) {
    a[0] += bflo(v.x); a[1] += bfhi(v.x);
    a[2] += bflo(v.y); a[3] += bfhi(v.y);
    a[4] += bflo(v.z); a[5] += bfhi(v.z);
    a[6] += bflo(v.w); a[7] += bfhi(v.w);
}

// intra-wave inclusive scan (6 shfl steps, no barriers)
__device__ __forceinline__ int wave_iscan(int s, int lane) {
    #pragma unroll
    for (int off = 1; off < 64; off <<= 1) {
        int t = __shfl_up(s, off);
        if (lane >= off) s += t;
    }
    return s;
}

// ============================ scatter + prep ============================
// all blocks: W fp32[k][n]->bf16 W^T[n][k] (4 mats) + x fp32->bf16 (grid-stride)
// blocks < SCHUNKS: stage EPB edges (src/dst register-cached: ONE global read),
// group by bucket in LDS, reserve global ranges, write grouped.
// Scan over bucket counts is wave-shfl based: 2 barriers total (was 18).
// packed edge: src (bits 0-15) | dst_local (bits 16-22) | bucket (bits 23-31)

__global__ __launch_bounds__(SBLOCK) void scatter_prep(
        const int* __restrict__ src, const int* __restrict__ dst,
        int* __restrict__ bcur, unsigned int* __restrict__ binned,
        const float* __restrict__ W0, const float* __restrict__ W1,
        const float* __restrict__ W2, const float* __restrict__ W3,
        unsigned short* __restrict__ Wt,
        const float4* __restrict__ xin, ushort4* __restrict__ xout) {
    __shared__ int lcnt[NB];
    __shared__ int gbase[NB];
    __shared__ int lcur[NB];
    __shared__ int wtot[8];
    __shared__ unsigned int staged[EPB];

    int tid = threadIdx.x;
    int blk = blockIdx.x;

    // ---- prep slice (independent of scatter) ----
    for (int idx = blk * SBLOCK + tid; idx < PREP_ELEMS; idx += SGRID * SBLOCK) {
        if (idx < 4 * F * F) {
            int m = idx >> 12;
            int e = idx & 4095;
            int n = e >> 6, k = e & 63;
            const float* W = (m == 0) ? W0 : (m == 1) ? W1 : (m == 2) ? W2 : W3;
            Wt[m * F * F + n * F + k] = f2bf(W[k * F + n]);
        } else {
            int i = idx - 4 * F * F;
            float4 v = xin[i];
            ushort4 o;
            o.x = f2bf(v.x); o.y = f2bf(v.y); o.z = f2bf(v.z); o.w = f2bf(v.w);
            xout[i] = o;
        }
    }

    if (blk >= SCHUNKS) return;                // block-uniform: whole block skips

    int lane = tid & 63;
    int wid  = tid >> 6;

    int e0 = blk * EPB;
    int e1 = min(N_EDGES, e0 + EPB);
    for (int i = tid; i < NB; i += SBLOCK) lcnt[i] = 0;
    __syncthreads();

    // register-cache the edges: one global read instead of two
    int dreg[4], sreg[4];
    #pragma unroll
    for (int t = 0; t < 4; ++t) {
        int i = e0 + tid + t * SBLOCK;
        if (i < e1) { dreg[t] = dst[i]; sreg[t] = src[i]; }
        else        { dreg[t] = -1;     sreg[t] = 0; }
    }
    #pragma unroll
    for (int t = 0; t < 4; ++t)
        if (dreg[t] >= 0) atomicAdd(&lcnt[dreg[t] >> 7], 1);
    __syncthreads();

    // wave-shfl inclusive scan over lcnt[0..NB) (padded with zeros to 512)
    int v = (tid < NB) ? lcnt[tid] : 0;
    int s = wave_iscan(v, lane);
    if (lane == 63) wtot[wid] = s;
    __syncthreads();
    int woff = 0;
    #pragma unroll
    for (int w = 0; w < 7; ++w)
        if (w < wid) woff += wtot[w];
    if (tid < NB) {
        int incl = s + woff;
        int excl = incl - v;
        int resv = (v > 0) ? atomicAdd(&bcur[tid], v) : 0;
        gbase[tid] = tid * BCAP + resv - excl;
        lcur[tid] = excl;
    }
    __syncthreads();

    #pragma unroll
    for (int t = 0; t < 4; ++t) {
        if (dreg[t] >= 0) {
            int d = dreg[t];
            int b = d >> 7;
            int dl = d & 127;
            int posl = atomicAdd(&lcur[b], 1);
            staged[posl] = (unsigned)sreg[t] | ((unsigned)dl << 16) | ((unsigned)b << 23);
        }
    }
    __syncthreads();

    int cnt = e1 - e0;
    for (int i = tid; i < cnt; i += SBLOCK) {
        unsigned pk = staged[i];
        binned[gbase[pk >> 23] + i] = pk;      // grouped -> mostly coalesced
    }
}

// ============================ bucket CSR build ============================
// per bucket: node counts + wave-shfl scan -> row_beg/degs/csr16 (binned reg-cached)
// 2 barriers in the scan path (was 14).

__global__ __launch_bounds__(512) void bucket_build(
        const unsigned int* __restrict__ binned, const int* __restrict__ bcur,
        int* __restrict__ row_beg, unsigned short* __restrict__ degs,
        unsigned short* __restrict__ csr16) {
    __shared__ int ncnt[BNODES];
    __shared__ int ncur[BNODES];
    __shared__ int w0tot;
    int blk = blockIdx.x;
    int tid = threadIdx.x;
    int lane = tid & 63;
    int wid  = tid >> 6;
    int start = blk * BCAP;
    int cnt = min(bcur[blk], BCAP);

    for (int i = tid; i < BNODES; i += 512) ncnt[i] = 0;
    __syncthreads();

    // register-cache bucket entries: one global read instead of two
    unsigned preg[5];
    #pragma unroll
    for (int t = 0; t < 5; ++t) {
        int i = tid + t * 512;
        preg[t] = (i < cnt) ? binned[start + i] : 0xFFFFFFFFu;
    }
    #pragma unroll
    for (int t = 0; t < 5; ++t)
        if (preg[t] != 0xFFFFFFFFu)
            atomicAdd(&ncnt[(preg[t] >> 16) & 127], 1);
    __syncthreads();

    // wave-shfl inclusive scan over ncnt[0..127] (waves 0,1 carry the data)
    int v = (tid < BNODES) ? ncnt[tid] : 0;
    int s = wave_iscan(v, lane);
    if (tid == 63) w0tot = s;
    __syncthreads();
    if (wid == 1) s += w0tot;
    if (tid < BNODES) {
        int excl = s - v;
        ncur[tid] = excl;
        int node = blk * BNODES + tid;
        row_beg[node] = start + excl;
        degs[node] = (unsigned short)v;
    }
    __syncthreads();

    #pragma unroll
    for (int t = 0; t < 5; ++t) {
        if (preg[t] != 0xFFFFFFFFu) {
            unsigned pk = preg[t];
            int dl = (pk >> 16) & 127;
            int pos = start + atomicAdd(&ncur[dl], 1);
            csr16[pos] = (unsigned short)(pk & 0xFFFF);
        }
    }
}

// ============ fused aggregate + MFMA transform: one block per 32-node tile ============
// Aggregation: 8 lanes per node x 8 nodes per wave, NO cross-lane reduce.
// Edge loop is 4-deep unrolled with ONE-QUAD-AHEAD index prefetch: csr16 indices
// for quad k+1 issue before the gathers of quad k are consumed, breaking the
// dependent csr16->xh8 two-hop latency chain. Tail handled by a clamped,
// predicated quad (no serial remainder).
// lagg is XOR-swizzled (col ^= row&7): the transform's 128B-stride ds_read_b128
// was a 16-way bank conflict, now 2-way (free).
// Then barrier; waves 0,1 each run the MFMA transform for one 16-node tile.
// PROJ=true fuses the layer-3 projection into p (neigh) / q (self).

template <bool PROJ>
__global__ __launch_bounds__(256) void aggtf_kernel(
        const uint4* __restrict__ xh8, const int* __restrict__ row_beg,
        const unsigned short* __restrict__ degs,
        const unsigned short* __restrict__ csr16,
        const uint4* __restrict__ Wst, const uint4* __restrict__ Wnt,
        const float* __restrict__ b, unsigned short* __restrict__ out_bf,
        const float* __restrict__ Ws3, const float* __restrict__ Wn3,
        float* __restrict__ pout, float* __restrict__ qout) {
    __shared__ uint4 lagg[32 * 8];             // 32 nodes x 64 feats bf16 (4 KB)
    int tid  = threadIdx.x;
    int wave = tid >> 6;
    int lane = tid & 63;
    int base = blockIdx.x * 32;

    int nsub = lane >> 3;                      // node within wave's 8
    int sub  = lane & 7;                       // ushort8 feature slice
    int node_l = wave * 8 + nsub;              // 0..31 within block

    // batched row metadata: lanes 0..31 load all 32 nodes, broadcast by shfl
    int rb_l = 0, dg_l = 0;
    if (lane < 32 && base + lane < N_NODES) {
        rb_l = row_beg[base + lane];
        dg_l = degs[base + lane];
    }
    int beg = __shfl(rb_l, node_l);
    int deg = __shfl(dg_l, node_l);
    int end = beg + deg;

    float a0[8], a1[8], a2[8], a3[8];
    #pragma unroll
    for (int j = 0; j < 8; ++j) { a0[j] = 0.f; a1[j] = 0.f; a2[j] = 0.f; a3[j] = 0.f; }

    int i = beg;
    int c0 = 0, c1 = 0, c2 = 0, c3 = 0;
    if (i < end) {                             // prefetch first quad (clamped)
        int el = end - 1;
        c0 = csr16[i];
        c1 = csr16[min(i + 1, el)];
        c2 = csr16[min(i + 2, el)];
        c3 = csr16[min(i + 3, el)];
    }
    while (i + 4 < end) {                      // full quad + next-quad prefetch
        int ni = i + 4;
        int el = end - 1;
        int n0 = csr16[ni];
        int n1 = csr16[min(ni + 1, el)];
        int n2 = csr16[min(ni + 2, el)];
        int n3 = csr16[min(ni + 3, el)];
        uint4 v0 = xh8[c0 * 8 + sub];
        uint4 v1 = xh8[c1 * 8 + sub];
        uint4 v2 = xh8[c2 * 8 + sub];
        uint4 v3 = xh8[c3 * 8 + sub];
        acc8(a0, v0); acc8(a1, v1); acc8(a2, v2); acc8(a3, v3);
        c0 = n0; c1 = n1; c2 = n2; c3 = n3;
        i = ni;
    }
    if (i < end) {                             // tail quad: clamped + predicated
        uint4 v0 = xh8[c0 * 8 + sub];
        uint4 v1 = xh8[c1 * 8 + sub];
        uint4 v2 = xh8[c2 * 8 + sub];
        uint4 v3 = xh8[c3 * 8 + sub];
        acc8(a0, v0);
        if (i + 1 < end) acc8(a1, v1);
        if (i + 2 < end) acc8(a2, v2);
        if (i + 3 < end) acc8(a3, v3);
    }
    {
        float inv = (deg > 0) ? (1.0f / (float)deg) : 0.f;
        unsigned short o[8];
        #pragma unroll
        for (int j = 0; j < 8; ++j)
            o[j] = f2bf(((a0[j] + a1[j]) + (a2[j] + a3[j])) * inv);
        uint4 pk;
        pk.x = (unsigned)o[0] | ((unsigned)o[1] << 16);
        pk.y = (unsigned)o[2] | ((unsigned)o[3] << 16);
        pk.z = (unsigned)o[4] | ((unsigned)o[5] << 16);
        pk.w = (unsigned)o[6] | ((unsigned)o[7] << 16);
        lagg[node_l * 8 + (sub ^ (node_l & 7))] = pk;   // XOR-swizzled slice
    }
    __syncthreads();

    if (wave >= 2) return;                     // 2 waves transform 2 tiles
    int tbase = base + wave * 16;
    if (tbase + 16 > N_NODES) return;          // N_NODES % 16 == 0: all-or-nothing

    int lo = lane & 15, hi = lane >> 4;

    frag16 ws[2][4], wn[2][4];
    #pragma unroll
    for (int kt = 0; kt < 2; ++kt)
        #pragma unroll
        for (int jt = 0; jt < 4; ++jt) {
            int n = jt * 16 + lo;
            ws[kt][jt].u = Wst[n * 8 + kt * 4 + hi];
            wn[kt][jt].u = Wnt[n * 8 + kt * 4 + hi];
        }
    float bias_s[4];
    #pragma unroll
    for (int jt = 0; jt < 4; ++jt) bias_s[jt] = b[jt * 16 + lo];
    float w3n_s[4], w3s_s[4];
    if constexpr (PROJ) {
        #pragma unroll
        for (int jt = 0; jt < 4; ++jt) {
            w3n_s[jt] = Wn3[jt * 16 + lo];
            w3s_s[jt] = Ws3[jt * 16 + lo];
        }
    }

    frag16 ax[2], aa[2];
    #pragma unroll
    for (int kt = 0; kt < 2; ++kt) {
        int row = wave * 16 + lo;
        ax[kt].u = xh8[(tbase + lo) * 8 + kt * 4 + hi];
        aa[kt].u = lagg[row * 8 + ((kt * 4 + hi) ^ (row & 7))];   // matching swizzle
    }

    f32x4 acc[4];
    #pragma unroll
    for (int jt = 0; jt < 4; ++jt)
        acc[jt] = f32x4{bias_s[jt], bias_s[jt], bias_s[jt], bias_s[jt]};

    #pragma unroll
    for (int kt = 0; kt < 2; ++kt)
        #pragma unroll
        for (int jt = 0; jt < 4; ++jt) {
            acc[jt] = __builtin_amdgcn_mfma_f32_16x16x32_bf16(ax[kt].s, ws[kt][jt].s, acc[jt], 0, 0, 0);
            acc[jt] = __builtin_amdgcn_mfma_f32_16x16x32_bf16(aa[kt].s, wn[kt][jt].s, acc[jt], 0, 0, 0);
        }

    if constexpr (!PROJ) {
        #pragma unroll
        for (int jt = 0; jt < 4; ++jt)
            #pragma unroll
            for (int r = 0; r < 4; ++r) {
                float h = fmaxf(acc[jt][r], 0.f);
                out_bf[(tbase + hi * 4 + r) * F + jt * 16 + lo] = f2bf(h);
            }
    } else {
        #pragma unroll
        for (int r = 0; r < 4; ++r) {
            float pr = 0.f, qr = 0.f;
            #pragma unroll
            for (int jt = 0; jt < 4; ++jt) {
                float h = fmaxf(acc[jt][r], 0.f);
                pr += h * w3n_s[jt];
                qr += h * w3s_s[jt];
            }
            #pragma unroll
            for (int off = 1; off < 16; off <<= 1) {
                pr += __shfl_xor(pr, off);
                qr += __shfl_xor(qr, off);
            }
            if (lo == 0) {
                pout[tbase + hi * 4 + r] = pr;
                qout[tbase + hi * 4 + r] = qr;
            }
        }
    }
}

// ================ final: out = q + mean_agg(p) + b3, 16 lanes per node ================

__global__ __launch_bounds__(256) void final_kernel(
        const int* __restrict__ row_beg, const unsigned short* __restrict__ degs,
        const unsigned short* __restrict__ csr16,
        const float* __restrict__ p, const float* __restrict__ q,
        const float* __restrict__ b3, float* __restrict__ out, int n_nodes) {
    int grp = threadIdx.x >> 4;
    int ln  = threadIdx.x & 15;
    int node = blockIdx.x * 16 + grp;
    if (node >= n_nodes) return;
    int beg = row_beg[node];
    int deg = degs[node];
    int end = beg + deg;
    float s = 0.f;
    for (int i = beg + ln; i < end; i += 16) s += p[csr16[i]];
    #pragma unroll
    for (int off = 1; off < 16; off <<= 1) s += __shfl_xor(s, off);
    if (ln == 0) {
        float inv = (deg > 0) ? (1.0f / (float)deg) : 0.f;
        out[node] = q[node] + s * inv + b3[0];
    }
}

// ---------------- launch ----------------

extern "C" void kernel_launch(void* const* d_in, const int* in_sizes, int n_in,
                              void* d_out, int out_size, void* d_ws, size_t ws_size,
                              hipStream_t stream) {
    const float* x   = (const float*)d_in[0];
    const int*   src = (const int*)d_in[1];
    const int*   dst = (const int*)d_in[2];
    const float* Ws1 = (const float*)d_in[3];
    const float* Wn1 = (const float*)d_in[4];
    const float* b1  = (const float*)d_in[5];
    const float* Ws2 = (const float*)d_in[6];
    const float* Wn2 = (const float*)d_in[7];
    const float* b2  = (const float*)d_in[8];
    const float* Ws3 = (const float*)d_in[9];
    const float* Wn3 = (const float*)d_in[10];
    const float* b3  = (const float*)d_in[11];
    float* out = (float*)d_out;

    char* ws = (char*)d_ws;
    size_t cur = 0;
    auto alloc = [&](size_t bytes) -> void* {
        void* ptr = ws + cur;
        cur += (bytes + 255) & ~(size_t)255;
        return ptr;
    };

    int*            bcur     = (int*)  alloc(NB * sizeof(int));
    unsigned int*   binned   = (unsigned int*)alloc((size_t)NB * BCAP * sizeof(unsigned int));
    int*            row_beg  = (int*)  alloc((size_t)(NB * BNODES) * sizeof(int));
    unsigned short* degs     = (unsigned short*)alloc((size_t)(NB * BNODES) * sizeof(unsigned short));
    unsigned short* csr16    = (unsigned short*)alloc((size_t)NB * BCAP * sizeof(unsigned short));
    unsigned short* xh       = (unsigned short*)alloc((size_t)N_NODES * F * 2);  // bf16 x
    unsigned short* h1h      = (unsigned short*)alloc((size_t)N_NODES * F * 2);  // bf16 h1
    unsigned short* Wt       = (unsigned short*)alloc(4 * F * F * 2);            // bf16 W^T x4
    float*          p        = (float*)alloc(N_NODES * sizeof(float));
    float*          q        = (float*)alloc(N_NODES * sizeof(float));

    unsigned short* Wst1 = Wt;
    unsigned short* Wnt1 = Wt + F * F;
    unsigned short* Wst2 = Wt + 2 * F * F;
    unsigned short* Wnt2 = Wt + 3 * F * F;

    (void)hipMemsetAsync(bcur, 0, NB * sizeof(int), stream);
    scatter_prep<<<SGRID, SBLOCK, 0, stream>>>(
        src, dst, bcur, binned, Ws1, Wn1, Ws2, Wn2, Wt, (const float4*)x, (ushort4*)xh);
    bucket_build<<<NB, 512, 0, stream>>>(binned, bcur, row_beg, degs, csr16);

    // layer 1: fused aggregate + transform
    aggtf_kernel<false><<<ATILES, 256, 0, stream>>>(
        (const uint4*)xh, row_beg, degs, csr16,
        (const uint4*)Wst1, (const uint4*)Wnt1, b1, h1h,
        nullptr, nullptr, nullptr, nullptr);
    // layer 2: fused aggregate + transform + layer-3 projection
    aggtf_kernel<true><<<ATILES, 256, 0, stream>>>(
        (const uint4*)h1h, row_beg, degs, csr16,
        (const uint4*)Wst2, (const uint4*)Wnt2, b2, nullptr,
        Ws3, Wn3, p, q);
    // layer 3: aggregate scalars
    final_kernel<<<(N_NODES + 15) / 16, 256, 0, stream>>>(
        row_beg, degs, csr16, p, q, b3, out, N_NODES);
}

// Round 6
// 152.765 us; speedup vs baseline: 3.7702x; 1.0013x over previous
//
#include <hip/hip_runtime.h>

#define N_NODES 50000
#define N_EDGES 800000
#define F 64
#define NTILES (N_NODES / 16)                  // 3125
#define ATILES ((N_NODES + 31) / 32)           // 1563 blocks (32 nodes each)

#define BNODES 128                             // nodes per bucket
#define NB ((N_NODES + BNODES - 1) / BNODES)   // 391 buckets
#define BCAP 2560                              // bucket capacity (mean 2046, +25% slack)
#define EPB 2048                               // edges per scatter chunk (4/thread @512)
#define SCHUNKS ((N_EDGES + EPB - 1) / EPB)    // 391 (last chunk 1280)
#define SGRID 512                              // scatter_prep grid
#define SBLOCK 512
#define PREP_ELEMS (4 * F * F + N_NODES * 16)  // W entries + float4 groups

typedef __attribute__((ext_vector_type(8))) short short8;   // 8 bf16 (4 VGPRs)
typedef __attribute__((ext_vector_type(4))) float f32x4;    // MFMA accumulator

union frag16 { uint4 u; short8 s; };

// ---------------- bf16 helpers (storage-only; all math fp32/MFMA) ----------------

__device__ __forceinline__ float bflo(unsigned int u) {
    union { unsigned int i; float f; } c; c.i = u << 16; return c.f;
}
__device__ __forceinline__ float bfhi(unsigned int u) {
    union { unsigned int i; float f; } c; c.i = u & 0xFFFF0000u; return c.f;
}
__device__ __forceinline__ unsigned short f2bf(float f) {   // round-nearest-even
    union { float f; unsigned int i; } c; c.f = f;
    unsigned int r = c.i + 0x7FFF + ((c.i >> 16) & 1);
    return (unsigned short)(r >> 16);
}

__device__ __forceinline__ void acc8(float* a, uint4 v) {
    a[0] += bflo(v.x); a[1] += bfhi(v.x);
    a[2] += bflo(v.y); a[3] += bfhi(v.y);
    a[4] += bflo(v.z); a[5] += bfhi(v.z);
    a[6] += bflo(v.w); a[7] += bfhi(v.w);
}

// intra-wave inclusive scan (6 shfl steps, no barriers)
__device__ __forceinline__ int wave_iscan(int s, int lane) {
    #pragma unroll
    for (int off = 1; off < 64; off <<= 1) {
        int t = __shfl_up(s, off);
        if (lane >= off) s += t;
    }
    return s;
}

// ============================ scatter + prep ============================
// all blocks: W fp32[k][n]->bf16 W^T[n][k] (4 mats) + x fp32->bf16 (grid-stride)
// blocks < SCHUNKS: stage EPB edges (src/dst register-cached: ONE global read),
// group by bucket in LDS, reserve global ranges, write grouped.
// Scan over bucket counts is wave-shfl based: 2 barriers total.
// packed edge: src (bits 0-15) | dst_local (bits 16-22) | bucket (bits 23-31)

__global__ __launch_bounds__(SBLOCK) void scatter_prep(
        const int* __restrict__ src, const int* __restrict__ dst,
        int* __restrict__ bcur, unsigned int* __restrict__ binned,
        const float* __restrict__ W0, const float* __restrict__ W1,
        const float* __restrict__ W2, const float* __restrict__ W3,
        unsigned short* __restrict__ Wt,
        const float4* __restrict__ xin, ushort4* __restrict__ xout) {
    __shared__ int lcnt[NB];
    __shared__ int gbase[NB];
    __shared__ int lcur[NB];
    __shared__ int wtot[8];
    __shared__ unsigned int staged[EPB];

    int tid = threadIdx.x;
    int blk = blockIdx.x;

    // ---- prep slice (independent of scatter) ----
    for (int idx = blk * SBLOCK + tid; idx < PREP_ELEMS; idx += SGRID * SBLOCK) {
        if (idx < 4 * F * F) {
            int m = idx >> 12;
            int e = idx & 4095;
            int n = e >> 6, k = e & 63;
            const float* W = (m == 0) ? W0 : (m == 1) ? W1 : (m == 2) ? W2 : W3;
            Wt[m * F * F + n * F + k] = f2bf(W[k * F + n]);
        } else {
            int i = idx - 4 * F * F;
            float4 v = xin[i];
            ushort4 o;
            o.x = f2bf(v.x); o.y = f2bf(v.y); o.z = f2bf(v.z); o.w = f2bf(v.w);
            xout[i] = o;
        }
    }

    if (blk >= SCHUNKS) return;                // block-uniform: whole block skips

    int lane = tid & 63;
    int wid  = tid >> 6;

    int e0 = blk * EPB;
    int e1 = min(N_EDGES, e0 + EPB);
    for (int i = tid; i < NB; i += SBLOCK) lcnt[i] = 0;
    __syncthreads();

    // register-cache the edges: one global read instead of two
    int dreg[4], sreg[4];
    #pragma unroll
    for (int t = 0; t < 4; ++t) {
        int i = e0 + tid + t * SBLOCK;
        if (i < e1) { dreg[t] = dst[i]; sreg[t] = src[i]; }
        else        { dreg[t] = -1;     sreg[t] = 0; }
    }
    #pragma unroll
    for (int t = 0; t < 4; ++t)
        if (dreg[t] >= 0) atomicAdd(&lcnt[dreg[t] >> 7], 1);
    __syncthreads();

    // wave-shfl inclusive scan over lcnt[0..NB) (padded with zeros to 512)
    int v = (tid < NB) ? lcnt[tid] : 0;
    int s = wave_iscan(v, lane);
    if (lane == 63) wtot[wid] = s;
    __syncthreads();
    int woff = 0;
    #pragma unroll
    for (int w = 0; w < 7; ++w)
        if (w < wid) woff += wtot[w];
    if (tid < NB) {
        int incl = s + woff;
        int excl = incl - v;
        int resv = (v > 0) ? atomicAdd(&bcur[tid], v) : 0;
        gbase[tid] = tid * BCAP + resv - excl;
        lcur[tid] = excl;
    }
    __syncthreads();

    #pragma unroll
    for (int t = 0; t < 4; ++t) {
        if (dreg[t] >= 0) {
            int d = dreg[t];
            int b = d >> 7;
            int dl = d & 127;
            int posl = atomicAdd(&lcur[b], 1);
            staged[posl] = (unsigned)sreg[t] | ((unsigned)dl << 16) | ((unsigned)b << 23);
        }
    }
    __syncthreads();

    int cnt = e1 - e0;
    for (int i = tid; i < cnt; i += SBLOCK) {
        unsigned pk = staged[i];
        binned[gbase[pk >> 23] + i] = pk;      // grouped -> mostly coalesced
    }
}

// ============================ bucket CSR build ============================
// per bucket: node counts + wave-shfl scan -> row_beg/degs/csr16 (binned reg-cached)

__global__ __launch_bounds__(512) void bucket_build(
        const unsigned int* __restrict__ binned, const int* __restrict__ bcur,
        int* __restrict__ row_beg, unsigned short* __restrict__ degs,
        unsigned short* __restrict__ csr16) {
    __shared__ int ncnt[BNODES];
    __shared__ int ncur[BNODES];
    __shared__ int w0tot;
    int blk = blockIdx.x;
    int tid = threadIdx.x;
    int lane = tid & 63;
    int wid  = tid >> 6;
    int start = blk * BCAP;
    int cnt = min(bcur[blk], BCAP);

    for (int i = tid; i < BNODES; i += 512) ncnt[i] = 0;
    __syncthreads();

    // register-cache bucket entries: one global read instead of two
    unsigned preg[5];
    #pragma unroll
    for (int t = 0; t < 5; ++t) {
        int i = tid + t * 512;
        preg[t] = (i < cnt) ? binned[start + i] : 0xFFFFFFFFu;
    }
    #pragma unroll
    for (int t = 0; t < 5; ++t)
        if (preg[t] != 0xFFFFFFFFu)
            atomicAdd(&ncnt[(preg[t] >> 16) & 127], 1);
    __syncthreads();

    // wave-shfl inclusive scan over ncnt[0..127] (waves 0,1 carry the data)
    int v = (tid < BNODES) ? ncnt[tid] : 0;
    int s = wave_iscan(v, lane);
    if (tid == 63) w0tot = s;
    __syncthreads();
    if (wid == 1) s += w0tot;
    if (tid < BNODES) {
        int excl = s - v;
        ncur[tid] = excl;
        int node = blk * BNODES + tid;
        row_beg[node] = start + excl;
        degs[node] = (unsigned short)v;
    }
    __syncthreads();

    #pragma unroll
    for (int t = 0; t < 5; ++t) {
        if (preg[t] != 0xFFFFFFFFu) {
            unsigned pk = preg[t];
            int dl = (pk >> 16) & 127;
            int pos = start + atomicAdd(&ncur[dl], 1);
            csr16[pos] = (unsigned short)(pk & 0xFFFF);
        }
    }
}

// ============ fused aggregate + MFMA transform: one block per 32-node tile ============
// OCCUPANCY-TUNED: __launch_bounds__(256,6) caps VGPR ~85 -> 6 waves/SIMD (24/CU),
// +50% latency hiding for the gather phase (was 4/SIMD at ~110 VGPR: the 16 W
// fragments were live across the whole kernel). To fit:
//  - aggregation uses 2 accumulator arrays (a0/a1 alternate over the 4-deep pipe)
//  - transform loads W fragments per-jt (4 live frags, not 16); W is L2-broadcast
// Aggregation: 8 lanes/node x 8 nodes/wave, no cross-lane reduce; 4-deep gather
// with one-quad-ahead csr16 index prefetch; clamped+predicated tail.
// lagg XOR-swizzled (16-way -> 2-way LDS bank conflict on the transform read).
// 1563 blocks == 6 blocks/CU x 256 CUs (grid exactly fills the occupancy).

template <bool PROJ>
__global__ __launch_bounds__(256, 6) void aggtf_kernel(
        const uint4* __restrict__ xh8, const int* __restrict__ row_beg,
        const unsigned short* __restrict__ degs,
        const unsigned short* __restrict__ csr16,
        const uint4* __restrict__ Wst, const uint4* __restrict__ Wnt,
        const float* __restrict__ b, unsigned short* __restrict__ out_bf,
        const float* __restrict__ Ws3, const float* __restrict__ Wn3,
        float* __restrict__ pout, float* __restrict__ qout) {
    __shared__ uint4 lagg[32 * 8];             // 32 nodes x 64 feats bf16 (4 KB)
    int tid  = threadIdx.x;
    int wave = tid >> 6;
    int lane = tid & 63;
    int base = blockIdx.x * 32;

    int nsub = lane >> 3;                      // node within wave's 8
    int sub  = lane & 7;                       // ushort8 feature slice
    int node_l = wave * 8 + nsub;              // 0..31 within block

    // batched row metadata: lanes 0..31 load all 32 nodes, broadcast by shfl
    int rb_l = 0, dg_l = 0;
    if (lane < 32 && base + lane < N_NODES) {
        rb_l = row_beg[base + lane];
        dg_l = degs[base + lane];
    }
    int beg = __shfl(rb_l, node_l);
    int deg = __shfl(dg_l, node_l);
    int end = beg + deg;

    float a0[8], a1[8];
    #pragma unroll
    for (int j = 0; j < 8; ++j) { a0[j] = 0.f; a1[j] = 0.f; }

    int i = beg;
    int c0 = 0, c1 = 0, c2 = 0, c3 = 0;
    if (i < end) {                             // prefetch first quad (clamped)
        int el = end - 1;
        c0 = csr16[i];
        c1 = csr16[min(i + 1, el)];
        c2 = csr16[min(i + 2, el)];
        c3 = csr16[min(i + 3, el)];
    }
    while (i + 4 < end) {                      // full quad + next-quad prefetch
        int ni = i + 4;
        int el = end - 1;
        int n0 = csr16[ni];
        int n1 = csr16[min(ni + 1, el)];
        int n2 = csr16[min(ni + 2, el)];
        int n3 = csr16[min(ni + 3, el)];
        uint4 v0 = xh8[c0 * 8 + sub];
        uint4 v1 = xh8[c1 * 8 + sub];
        uint4 v2 = xh8[c2 * 8 + sub];
        uint4 v3 = xh8[c3 * 8 + sub];
        acc8(a0, v0); acc8(a1, v1); acc8(a0, v2); acc8(a1, v3);
        c0 = n0; c1 = n1; c2 = n2; c3 = n3;
        i = ni;
    }
    if (i < end) {                             // tail quad: clamped + predicated
        uint4 v0 = xh8[c0 * 8 + sub];
        uint4 v1 = xh8[c1 * 8 + sub];
        uint4 v2 = xh8[c2 * 8 + sub];
        uint4 v3 = xh8[c3 * 8 + sub];
        acc8(a0, v0);
        if (i + 1 < end) acc8(a1, v1);
        if (i + 2 < end) acc8(a0, v2);
        if (i + 3 < end) acc8(a1, v3);
    }
    {
        float inv = (deg > 0) ? (1.0f / (float)deg) : 0.f;
        unsigned short o[8];
        #pragma unroll
        for (int j = 0; j < 8; ++j)
            o[j] = f2bf((a0[j] + a1[j]) * inv);
        uint4 pk;
        pk.x = (unsigned)o[0] | ((unsigned)o[1] << 16);
        pk.y = (unsigned)o[2] | ((unsigned)o[3] << 16);
        pk.z = (unsigned)o[4] | ((unsigned)o[5] << 16);
        pk.w = (unsigned)o[6] | ((unsigned)o[7] << 16);
        lagg[node_l * 8 + (sub ^ (node_l & 7))] = pk;   // XOR-swizzled slice
    }
    __syncthreads();

    if (wave >= 2) return;                     // 2 waves transform 2 tiles
    int tbase = base + wave * 16;
    if (tbase + 16 > N_NODES) return;          // N_NODES % 16 == 0: all-or-nothing

    int lo = lane & 15, hi = lane >> 4;

    float bias_s[4];
    #pragma unroll
    for (int jt = 0; jt < 4; ++jt) bias_s[jt] = b[jt * 16 + lo];
    float w3n_s[4], w3s_s[4];
    if constexpr (PROJ) {
        #pragma unroll
        for (int jt = 0; jt < 4; ++jt) {
            w3n_s[jt] = Wn3[jt * 16 + lo];
            w3s_s[jt] = Ws3[jt * 16 + lo];
        }
    }

    frag16 ax[2], aa[2];
    #pragma unroll
    for (int kt = 0; kt < 2; ++kt) {
        int row = wave * 16 + lo;
        ax[kt].u = xh8[(tbase + lo) * 8 + kt * 4 + hi];
        aa[kt].u = lagg[row * 8 + ((kt * 4 + hi) ^ (row & 7))];   // matching swizzle
    }

    f32x4 acc[4];
    #pragma unroll
    for (int jt = 0; jt < 4; ++jt)
        acc[jt] = f32x4{bias_s[jt], bias_s[jt], bias_s[jt], bias_s[jt]};

    // per-jt W loading: only 4 fragments live at a time (VGPR budget),
    // same per-acc MFMA order as before (kt0:ws,wn then kt1:ws,wn) -> bit-identical
    #pragma unroll
    for (int jt = 0; jt < 4; ++jt) {
        int n = jt * 16 + lo;
        frag16 ws0, wn0, ws1, wn1;
        ws0.u = Wst[n * 8 + 0 + hi];
        wn0.u = Wnt[n * 8 + 0 + hi];
        ws1.u = Wst[n * 8 + 4 + hi];
        wn1.u = Wnt[n * 8 + 4 + hi];
        acc[jt] = __builtin_amdgcn_mfma_f32_16x16x32_bf16(ax[0].s, ws0.s, acc[jt], 0, 0, 0);
        acc[jt] = __builtin_amdgcn_mfma_f32_16x16x32_bf16(aa[0].s, wn0.s, acc[jt], 0, 0, 0);
        acc[jt] = __builtin_amdgcn_mfma_f32_16x16x32_bf16(ax[1].s, ws1.s, acc[jt], 0, 0, 0);
        acc[jt] = __builtin_amdgcn_mfma_f32_16x16x32_bf16(aa[1].s, wn1.s, acc[jt], 0, 0, 0);
    }

    if constexpr (!PROJ) {
        #pragma unroll
        for (int jt = 0; jt < 4; ++jt)
            #pragma unroll
            for (int r = 0; r < 4; ++r) {
                float h = fmaxf(acc[jt][r], 0.f);
                out_bf[(tbase + hi * 4 + r) * F + jt * 16 + lo] = f2bf(h);
            }
    } else {
        #pragma unroll
        for (int r = 0; r < 4; ++r) {
            float pr = 0.f, qr = 0.f;
            #pragma unroll
            for (int jt = 0; jt < 4; ++jt) {
                float h = fmaxf(acc[jt][r], 0.f);
                pr += h * w3n_s[jt];
                qr += h * w3s_s[jt];
            }
            #pragma unroll
            for (int off = 1; off < 16; off <<= 1) {
                pr += __shfl_xor(pr, off);
                qr += __shfl_xor(qr, off);
            }
            if (lo == 0) {
                pout[tbase + hi * 4 + r] = pr;
                qout[tbase + hi * 4 + r] = qr;
            }
        }
    }
}

// ================ final: out = q + mean_agg(p) + b3, 16 lanes per node ================

__global__ __launch_bounds__(256) void final_kernel(
        const int* __restrict__ row_beg, const unsigned short* __restrict__ degs,
        const unsigned short* __restrict__ csr16,
        const float* __restrict__ p, const float* __restrict__ q,
        const float* __restrict__ b3, float* __restrict__ out, int n_nodes) {
    int grp = threadIdx.x >> 4;
    int ln  = threadIdx.x & 15;
    int node = blockIdx.x * 16 + grp;
    if (node >= n_nodes) return;
    int beg = row_beg[node];
    int deg = degs[node];
    int end = beg + deg;
    float s = 0.f;
    for (int i = beg + ln; i < end; i += 16) s += p[csr16[i]];
    #pragma unroll
    for (int off = 1; off < 16; off <<= 1) s += __shfl_xor(s, off);
    if (ln == 0) {
        float inv = (deg > 0) ? (1.0f / (float)deg) : 0.f;
        out[node] = q[node] + s * inv + b3[0];
    }
}

// ---------------- launch ----------------

extern "C" void kernel_launch(void* const* d_in, const int* in_sizes, int n_in,
                              void* d_out, int out_size, void* d_ws, size_t ws_size,
                              hipStream_t stream) {
    const float* x   = (const float*)d_in[0];
    const int*   src = (const int*)d_in[1];
    const int*   dst = (const int*)d_in[2];
    const float* Ws1 = (const float*)d_in[3];
    const float* Wn1 = (const float*)d_in[4];
    const float* b1  = (const float*)d_in[5];
    const float* Ws2 = (const float*)d_in[6];
    const float* Wn2 = (const float*)d_in[7];
    const float* b2  = (const float*)d_in[8];
    const float* Ws3 = (const float*)d_in[9];
    const float* Wn3 = (const float*)d_in[10];
    const float* b3  = (const float*)d_in[11];
    float* out = (float*)d_out;

    char* ws = (char*)d_ws;
    size_t cur = 0;
    auto alloc = [&](size_t bytes) -> void* {
        void* ptr = ws + cur;
        cur += (bytes + 255) & ~(size_t)255;
        return ptr;
    };

    int*            bcur     = (int*)  alloc(NB * sizeof(int));
    unsigned int*   binned   = (unsigned int*)alloc((size_t)NB * BCAP * sizeof(unsigned int));
    int*            row_beg  = (int*)  alloc((size_t)(NB * BNODES) * sizeof(int));
    unsigned short* degs     = (unsigned short*)alloc((size_t)(NB * BNODES) * sizeof(unsigned short));
    unsigned short* csr16    = (unsigned short*)alloc((size_t)NB * BCAP * sizeof(unsigned short));
    unsigned short* xh       = (unsigned short*)alloc((size_t)N_NODES * F * 2);  // bf16 x
    unsigned short* h1h      = (unsigned short*)alloc((size_t)N_NODES * F * 2);  // bf16 h1
    unsigned short* Wt       = (unsigned short*)alloc(4 * F * F * 2);            // bf16 W^T x4
    float*          p        = (float*)alloc(N_NODES * sizeof(float));
    float*          q        = (float*)alloc(N_NODES * sizeof(float));

    unsigned short* Wst1 = Wt;
    unsigned short* Wnt1 = Wt + F * F;
    unsigned short* Wst2 = Wt + 2 * F * F;
    unsigned short* Wnt2 = Wt + 3 * F * F;

    (void)hipMemsetAsync(bcur, 0, NB * sizeof(int), stream);
    scatter_prep<<<SGRID, SBLOCK, 0, stream>>>(
        src, dst, bcur, binned, Ws1, Wn1, Ws2, Wn2, Wt, (const float4*)x, (ushort4*)xh);
    bucket_build<<<NB, 512, 0, stream>>>(binned, bcur, row_beg, degs, csr16);

    // layer 1: fused aggregate + transform
    aggtf_kernel<false><<<ATILES, 256, 0, stream>>>(
        (const uint4*)xh, row_beg, degs, csr16,
        (const uint4*)Wst1, (const uint4*)Wnt1, b1, h1h,
        nullptr, nullptr, nullptr, nullptr);
    // layer 2: fused aggregate + transform + layer-3 projection
    aggtf_kernel<true><<<ATILES, 256, 0, stream>>>(
        (const uint4*)h1h, row_beg, degs, csr16,
        (const uint4*)Wst2, (const uint4*)Wnt2, b2, nullptr,
        Ws3, Wn3, p, q);
    // layer 3: aggregate scalars
    final_kernel<<<(N_NODES + 15) / 16, 256, 0, stream>>>(
        row_beg, degs, csr16, p, q, b3, out, N_NODES);
}